// Round 1
// baseline (198397.583 us; speedup 1.0000x reference)
//
#include <hip/hip_runtime.h>
#include <cstdint>

#define BB 32
#define TT 256
#define LSEQ 256
#define NBLK 256
#define BN_INV 0.99999500003750f

struct Args {
  const float *enc_z, *ys;
  const int* ilens;
  const float *W_enc, *b_enc, *W_dec, *loc_kernel, *W_att, *g_w, *g_b;
  const float *Wp0, *bp0, *Wp1, *bp1;
  const float *Wih0, *Whh0, *bih0, *bhh0, *Wih1, *Whh1, *bih1, *bhh1;
  const float *Wf, *bf, *Wq, *bq;
  const float *pk0,*pb0,*bg0,*bb0,*pk1,*pb1,*bg1,*bb1,*pk2,*pb2,*bg2,*bb2;
  float *enc_proj, *pre_tmp, *pre_all, *G, *aw0, *p_buf, *sum_buf, *dec, *att_c;
  float *z0, *c0, *z1a, *z1b, *c1, *gates_part, *bias0, *bias1;
  float *part0, *part1, *part2;
  float *before_t, *h0, *h1, *Wt0, *Wt1, *Wt2, *s0, *t0s, *s1, *t1s, *s2, *t2s;
  int* cnt;
  float *out_after, *out_before, *out_logits, *out_aws;
};

__device__ __forceinline__ float sigf(float x){ return 1.0f/(1.0f+expf(-x)); }

__device__ __forceinline__ void gbar(int* cnt, int target){
  __syncthreads();
  if (threadIdx.x == 0){
    __threadfence();
    __hip_atomic_fetch_add(cnt, 1, __ATOMIC_ACQ_REL, __HIP_MEMORY_SCOPE_AGENT);
    while (__hip_atomic_load(cnt, __ATOMIC_ACQUIRE, __HIP_MEMORY_SCOPE_AGENT) < target){
      __builtin_amdgcn_s_sleep(2);
    }
    __threadfence();
  }
  __syncthreads();
}

// ---------------- init: small precomputes ----------------
__global__ void k_init(Args A){
  int tid0 = blockIdx.x*blockDim.x + threadIdx.x;
  int stride = gridDim.x*blockDim.x;
  // G[k][d] = sum_c W_att[c,d] * loc_kernel[c,0,k]
  for (int i = tid0; i < 31*128; i += stride){
    int k = i >> 7, d = i & 127;
    float s = 0.f;
    for (int c = 0; c < 32; ++c) s += A.W_att[c*128+d]*A.loc_kernel[c*31+k];
    A.G[i] = s;
  }
  for (int i = tid0; i < 2048; i += stride){
    A.bias0[i] = A.bih0[i]+A.bhh0[i];
    A.bias1[i] = A.bih1[i]+A.bhh1[i];
  }
  for (int i = tid0; i < 32*512; i += stride){ A.z0[i]=0.f; A.c0[i]=0.f; A.z1a[i]=0.f; A.c1[i]=0.f; }
  for (int i = tid0; i < 32*128; i += stride) A.dec[i]=0.f;
  if (tid0 < 32) A.sum_buf[tid0]=0.f;
  if (tid0 == 0) *A.cnt = 0;
  for (int i = tid0; i < 32*256; i += stride){
    int b = i>>8, t = i&255; int il = A.ilens[b];
    A.aw0[i] = (t < il) ? 1.0f/(float)il : 0.0f;
  }
  for (int i = tid0; i < 512; i += stride){
    float s = A.bg0[i]*BN_INV; A.s0[i]=s; A.t0s[i]=s*A.pb0[i]+A.bb0[i];
    float u = A.bg1[i]*BN_INV; A.s1[i]=u; A.t1s[i]=u*A.pb1[i]+A.bb1[i];
  }
  for (int i = tid0; i < 80; i += stride){
    float s = A.bg2[i]*BN_INV; A.s2[i]=s; A.t2s[i]=s*A.pb2[i]+A.bb2[i];
  }
  // Wt[k][c][n] = pk[n][c][k]
  for (int i = tid0; i < 5*80*512; i += stride){
    int k = i/(80*512); int r = i - k*(80*512); int c = r>>9, n = r&511;
    A.Wt0[i] = A.pk0[(n*80+c)*5+k];
  }
  for (int i = tid0; i < 5*512*512; i += stride){
    int k = i/(512*512); int r = i - k*(512*512); int c = r>>9, n = r&511;
    A.Wt1[i] = A.pk1[(n*512+c)*5+k];
  }
  for (int i = tid0; i < 5*512*80; i += stride){
    int k = i/(512*80); int r = i - k*(512*80); int c = r/80, n = r - c*80;
    A.Wt2[i] = A.pk2[(n*512+c)*5+k];
  }
}

// ---------------- enc_proj = enc_z @ W_enc + b_enc ----------------
__global__ void __launch_bounds__(256) k_encproj(Args A){
  __shared__ __align__(16) float As[32][128];
  int m0 = blockIdx.x*32;
  int tid = threadIdx.x;
  int d = tid & 127, half = tid >> 7;
  float acc[16];
  #pragma unroll
  for (int r = 0; r < 16; ++r) acc[r] = 0.f;
  for (int j0 = 0; j0 < 512; j0 += 128){
    for (int i = 0; i < 16; ++i){
      int e = tid + i*256; int r = e >> 7, j = e & 127;
      As[r][j] = A.enc_z[(size_t)(m0+r)*512 + j0 + j];
    }
    __syncthreads();
    for (int j = 0; j < 128; ++j){
      float w = A.W_enc[(size_t)(j0+j)*128 + d];
      #pragma unroll
      for (int r = 0; r < 16; ++r) acc[r] += As[half*16+r][j]*w;
    }
    __syncthreads();
  }
  float be = A.b_enc[d];
  for (int r = 0; r < 16; ++r)
    A.enc_proj[(size_t)(m0+half*16+r)*128 + d] = acc[r] + be;
}

// ---------------- prenet layer 0 ----------------
__global__ void __launch_bounds__(256) k_pre0(Args A){
  __shared__ float As[32][80];
  int m0 = blockIdx.x*32, tid = threadIdx.x;
  for (int e = tid; e < 2560; e += 256){
    int r = e/80, o = e - r*80;
    int row = m0+r; int l = row & 255, b = row >> 8;
    As[r][o] = (l==0) ? 0.f : A.ys[((size_t)b*256 + (l-1))*80 + o];
  }
  __syncthreads();
  float acc[32];
  #pragma unroll
  for (int r = 0; r < 32; ++r) acc[r] = 0.f;
  for (int o = 0; o < 80; ++o){
    float w = A.Wp0[o*256 + tid];
    #pragma unroll
    for (int r = 0; r < 32; ++r) acc[r] += As[r][o]*w;
  }
  float bb = A.bp0[tid];
  for (int r = 0; r < 32; ++r){
    float v = acc[r]+bb;
    A.pre_tmp[(size_t)(m0+r)*256 + tid] = v>0.f?v:0.f;
  }
}

// ---------------- prenet layer 1 ----------------
__global__ void __launch_bounds__(256) k_pre1(Args A){
  __shared__ float As[32][256];
  int m0 = blockIdx.x*32, tid = threadIdx.x;
  for (int e = tid; e < 8192; e += 256){
    int r = e >> 8, j = e & 255;
    As[r][j] = A.pre_tmp[(size_t)(m0+r)*256 + j];
  }
  __syncthreads();
  float acc[32];
  #pragma unroll
  for (int r = 0; r < 32; ++r) acc[r] = 0.f;
  for (int j = 0; j < 256; ++j){
    float w = A.Wp1[j*256 + tid];
    #pragma unroll
    for (int r = 0; r < 32; ++r) acc[r] += As[r][j]*w;
  }
  float bb = A.bp1[tid];
  for (int r = 0; r < 32; ++r){
    float v = acc[r]+bb;
    A.pre_all[(size_t)(m0+r)*256 + tid] = v>0.f?v:0.f;
  }
}

// GEMM partial: Spart[b][col0+cg*4..] = sum_{j<KS} X[b][j] * W[j][col]
// block tiles: 32 cols (8 groups of 4) x all 32 b; weights read once per block.
__device__ __forceinline__ void gemm_part(const float* __restrict__ W,
                                          const float* __restrict__ Xg, int xstride,
                                          int kshift, int col0,
                                          float* __restrict__ Spart,
                                          float* __restrict__ Xlds, int tid)
{
  const int KS = 1 << kshift;
  const int pitch = KS + 1;
  for (int e = tid; e < 32*KS; e += 256){
    int b = e >> kshift, j = e & (KS-1);
    Xlds[b*pitch + j] = Xg[(size_t)b*xstride + j];
  }
  __syncthreads();
  const int cg = tid & 7, b = tid >> 3;
  const int col = col0 + cg*4;
  const float* xr = Xlds + b*pitch;
  const float* wc = W + col;
  float ax=0.f, ay=0.f, az=0.f, aw=0.f;
  #pragma unroll 4
  for (int j = 0; j < KS; ++j){
    float x = xr[j];
    const float4 w = *reinterpret_cast<const float4*>(wc + (size_t)j*2048);
    ax += x*w.x; ay += x*w.y; az += x*w.z; aw += x*w.w;
  }
  float4 r; r.x=ax; r.y=ay; r.z=az; r.w=aw;
  *reinterpret_cast<float4*>(Spart + b*2048 + col) = r;
  __syncthreads();
}

#define GBAR() do { bar_t += NBLK; gbar(A.cnt, bar_t); } while(0)

// ---------------- the scan: persistent kernel, custom grid barrier ----------------
__global__ void __launch_bounds__(256) k_scan(Args A){
  __shared__ __align__(16) float Gs[3968];
  __shared__ __align__(16) float S[8224];   // 32*257 floats max (GEMM X stage)
  const int blk = blockIdx.x, tid = threadIdx.x;
  int bar_t = 0;

  for (int e = tid; e < 3968; e += 256) Gs[e] = A.G[e];

  // Ph0: gates_part(t=0) = bias0 + pre(0) @ Wih0[512:768]
  {
    int b = blk>>3, n0 = (blk&7)*256;
    float* pl = S;
    pl[tid] = A.pre_all[(size_t)b*65536 + tid];   // row l = 0
    __syncthreads();
    int n = n0 + tid;
    float g = A.bias0[n];
    for (int j = 0; j < 256; ++j) g += pl[j]*A.Wih0[(size_t)(512+j)*2048 + n];
    A.gates_part[b*2048 + n] = g;
  }
  GBAR();

  for (int t = 0; t < LSEQ; ++t){
    const float* z1rd = (t&1) ? A.z1b : A.z1a;
    float*       z1wr = (t&1) ? A.z1a : A.z1b;

    // ---- Ph1: e -> p=exp(2e), per-b sums; also out/logit for step t-1 ----
    {
      int b = blk>>3, t0 = (blk&7)*32;
      const float* awp = (t==0) ? (A.aw0 + b*256)
                                : (A.out_aws + ((size_t)b*256 + (t-1))*256);
      float* awin = S;        // 62
      float* decs = S + 64;   // 128
      float* gws  = S + 192;  // 128
      float* psum = S + 320;  // 32
      if (tid < 128) decs[tid] = A.dec[b*128 + tid];
      else           gws[tid-128] = A.g_w[tid-128];
      if (tid < 62){ int ix = t0 - 15 + tid; awin[tid] = ((unsigned)ix < 256u) ? awp[ix] : 0.f; }
      __syncthreads();
      int lane = tid & 7, tl = tid >> 3;
      int tt = t0 + tl, d0 = lane*16;
      float att[16];
      #pragma unroll
      for (int i = 0; i < 16; ++i) att[i] = 0.f;
      for (int k = 0; k < 31; ++k){
        float a = awin[tl + k];
        const float* gp = &Gs[k*128 + d0];
        #pragma unroll
        for (int i = 0; i < 16; ++i) att[i] += gp[i]*a;
      }
      const float* ep = A.enc_proj + ((size_t)b*256 + tt)*128 + d0;
      float part = 0.f;
      #pragma unroll
      for (int i = 0; i < 16; ++i){
        float v = att[i] + ep[i] + decs[d0+i];
        part += tanhf(v)*gws[d0+i];
      }
      part += __shfl_xor(part,1); part += __shfl_xor(part,2); part += __shfl_xor(part,4);
      if (lane == 0){
        float e = part + A.g_b[0];
        float p = (tt < A.ilens[b]) ? expf(2.0f*e) : 0.0f;   // SCALING=2; masked -> 0
        A.p_buf[b*256 + tt] = p;
        psum[tl] = p;
      }
      __syncthreads();
      if (tid == 0){
        float ssum = 0.f;
        for (int i = 0; i < 32; ++i) ssum += psum[i];
        atomicAdd(A.sum_buf + b, ssum);
      }
      if ((blk&7)==7 && t > 0 && tid <= 80){
        bool isо = tid < 80;
        int st = isо ? 80 : 1;
        const float* Wv = isо ? (A.Wf + tid) : A.Wq;
        float acc = isо ? A.bf[tid] : A.bq[0];
        const float* z1p = z1rd + b*512;          // z1 state after step t-1
        const float* acp = A.att_c + b*512;       // att_c of step t-1 (not yet overwritten)
        for (int j = 0; j < 512; ++j) acc += z1p[j]*Wv[(size_t)j*st];
        for (int j = 0; j < 512; ++j) acc += acp[j]*Wv[(size_t)(512+j)*st];
        int to = t-1;
        if (isо){
          A.out_before[((size_t)b*256 + to)*80 + tid] = acc;
          A.before_t[((size_t)b*80 + tid)*256 + to] = acc;
        } else {
          A.out_logits[(size_t)b*256 + to] = acc;
        }
      }
    }
    GBAR();

    // ---- Ph2: att_c = (p @ enc_z)/sum ; write normalized aw ----
    {
      int b = blk>>3, chunk = blk&7;
      int dd = tid & 63, g = tid >> 6;
      int d = chunk*64 + dd;
      float inv = 1.0f / A.sum_buf[b];
      const float* pp = A.p_buf + b*256;
      const float* ez = A.enc_z + ((size_t)b*256)*512 + d;
      float partial = 0.f;
      for (int q = g*64; q < g*64+64; ++q) partial += pp[q]*ez[(size_t)q*512];
      float* red = S;
      red[g*64 + dd] = partial;
      __syncthreads();
      if (g == 0){
        float v = red[dd] + red[64+dd] + red[128+dd] + red[192+dd];
        A.att_c[b*512 + d] = v*inv;
      }
      if (chunk == 0) A.out_aws[((size_t)b*256 + t)*256 + tid] = pp[tid]*inv;
    }
    GBAR();

    // ---- Ph3a: LSTM0 att-part GEMM partials (K=512, 4 slices of 128) ----
    {
      int chunk = blk & 63, s = blk >> 6;
      gemm_part(A.Wih0 + (size_t)(s*128)*2048, A.att_c + s*128, 512, 7,
                chunk*32, A.part0 + s*65536, S, tid);
    }
    GBAR();

    // ---- Ph3b: LSTM0 finalize + zoneout ----
    {
      int b = blk>>3, chunk = blk&7;
      if (tid < 64){
        int u = chunk*64 + tid;
        const float* gp = A.gates_part + b*2048;
        const float* p0 = A.part0 + b*2048;
        float gi = gp[u]      + p0[u]      + p0[65536+u]      + p0[131072+u]      + p0[196608+u];
        float gf = gp[u+512]  + p0[u+512]  + p0[65536+u+512]  + p0[131072+u+512]  + p0[196608+u+512];
        float gg = gp[u+1024] + p0[u+1024] + p0[65536+u+1024] + p0[131072+u+1024] + p0[196608+u+1024];
        float go = gp[u+1536] + p0[u+1536] + p0[65536+u+1536] + p0[131072+u+1536] + p0[196608+u+1536];
        float c_old = A.c0[b*512+u], z_old = A.z0[b*512+u];
        float c2 = sigf(gf)*c_old + sigf(gi)*tanhf(gg);
        float h  = sigf(go)*tanhf(c2);
        A.c0[b*512+u] = 0.1f*c_old + 0.9f*c2;
        A.z0[b*512+u] = 0.1f*z_old + 0.9f*h;
      }
    }
    GBAR();

    // ---- Ph4a: LSTM1 GEMM partials (K=1024) + next-step gates_part GEMM (K=768) ----
    {
      int chunk = blk & 63, s = blk >> 6;
      {
        const float* W  = (s<2) ? (A.Wih1 + (size_t)(s*256)*2048)
                                : (A.Whh1 + (size_t)((s-2)*256)*2048);
        const float* Xg = (s<2) ? (A.z0 + s*256) : (z1rd + (s-2)*256);
        gemm_part(W, Xg, 512, 8, chunk*32, A.part1 + s*65536, S, tid);
      }
      if (t < 255){
        if (s < 2){
          gemm_part(A.Whh0 + (size_t)(s*256)*2048, A.z0 + s*256, 512, 8,
                    chunk*32, A.part2 + s*65536, S, tid);
        } else {
          gemm_part(A.Wih0 + (size_t)(512+(s-2)*128)*2048,
                    A.pre_all + (size_t)(t+1)*256 + (s-2)*128, 65536, 7,
                    chunk*32, A.part2 + s*65536, S, tid);
        }
      }
    }
    GBAR();

    // ---- Ph4b: LSTM1 finalize + gates_part finalize + dec(t+1) + sum reset ----
    {
      int b = blk>>3, chunk = blk&7;
      if (tid < 64){
        int u = chunk*64 + tid;
        const float* p1 = A.part1 + b*2048;
        float gi = A.bias1[u]      + p1[u]      + p1[65536+u]      + p1[131072+u]      + p1[196608+u];
        float gf = A.bias1[u+512]  + p1[u+512]  + p1[65536+u+512]  + p1[131072+u+512]  + p1[196608+u+512];
        float gg = A.bias1[u+1024] + p1[u+1024] + p1[65536+u+1024] + p1[131072+u+1024] + p1[196608+u+1024];
        float go = A.bias1[u+1536] + p1[u+1536] + p1[65536+u+1536] + p1[131072+u+1536] + p1[196608+u+1536];
        float c_old = A.c1[b*512+u];
        float z_old = z1rd[b*512+u];
        float c2 = sigf(gf)*c_old + sigf(gi)*tanhf(gg);
        float h  = sigf(go)*tanhf(c2);
        A.c1[b*512+u] = 0.1f*c_old + 0.9f*c2;
        z1wr[b*512+u] = 0.1f*z_old + 0.9f*h;
      }
      if (t < 255){
        int n = chunk*256 + tid;
        const float* p2 = A.part2 + b*2048;
        A.gates_part[b*2048+n] = A.bias0[n] + p2[n] + p2[65536+n] + p2[131072+n] + p2[196608+n];
        if (chunk == 0 && tid < 128){
          float dv = 0.f;
          const float* z0p = A.z0 + b*512;
          for (int j = 0; j < 512; ++j) dv += z0p[j]*A.W_dec[j*128 + tid];
          A.dec[b*128 + tid] = dv;
        }
      }
      if (blk == 0 && tid < 32) A.sum_buf[tid] = 0.f;
    }
    GBAR();
  }

  // tail: out/logit for t=255 (z1 state = z1a since write(255) -> z1a)
  if ((blk&7)==7 && tid <= 80){
    int b = blk>>3;
    bool isо = tid < 80;
    int st = isо ? 80 : 1;
    const float* Wv = isо ? (A.Wf + tid) : A.Wq;
    float acc = isо ? A.bf[tid] : A.bq[0];
    const float* z1p = A.z1a + b*512;
    const float* acp = A.att_c + b*512;
    for (int j = 0; j < 512; ++j) acc += z1p[j]*Wv[(size_t)j*st];
    for (int j = 0; j < 512; ++j) acc += acp[j]*Wv[(size_t)(512+j)*st];
    if (isо){
      A.out_before[((size_t)b*256 + 255)*80 + tid] = acc;
      A.before_t[((size_t)b*80 + tid)*256 + 255] = acc;
    } else {
      A.out_logits[(size_t)b*256 + 255] = acc;
    }
  }
}

// ---------------- postnet conv (kernel=5, pad=2) as tiled GEMM ----------------
__global__ void __launch_bounds__(256) k_conv(const float* __restrict__ in,
                       const float* __restrict__ Wt,  // (5, C, N)
                       const float* __restrict__ sc, const float* __restrict__ sh,
                       float* __restrict__ out0, const float* __restrict__ before,
                       float* __restrict__ after, int C, int N, int mode)
{
  __shared__ __align__(16) float As[16][64];
  __shared__ __align__(16) float Bs[16][64];
  int bx = blockIdx.x;
  int b = bx >> 2, l0 = (bx & 3)*64;
  int n0 = blockIdx.y*64;
  int tid = threadIdx.x, tx = tid & 15, ty = tid >> 4;
  float acc[4][4];
  #pragma unroll
  for (int i = 0; i < 4; ++i)
    #pragma unroll
    for (int j = 0; j < 4; ++j) acc[i][j] = 0.f;
  for (int k = 0; k < 5; ++k){
    int shift = k - 2;
    for (int c0 = 0; c0 < C; c0 += 16){
      #pragma unroll
      for (int i = 0; i < 4; ++i){
        int e = tid + i*256; int cc = e >> 6, ll = e & 63;
        int l = l0 + ll + shift;
        As[cc][ll] = ((unsigned)l < 256u) ? in[((size_t)(b*C + c0+cc))*256 + l] : 0.f;
        int n = n0 + ll;
        Bs[cc][ll] = (n < N) ? Wt[((size_t)k*C + c0+cc)*(size_t)N + n] : 0.f;
      }
      __syncthreads();
      #pragma unroll
      for (int cc = 0; cc < 16; ++cc){
        const float4 av = *reinterpret_cast<const float4*>(&As[cc][ty<<2]);
        const float4 bv = *reinterpret_cast<const float4*>(&Bs[cc][tx<<2]);
        acc[0][0]+=av.x*bv.x; acc[0][1]+=av.x*bv.y; acc[0][2]+=av.x*bv.z; acc[0][3]+=av.x*bv.w;
        acc[1][0]+=av.y*bv.x; acc[1][1]+=av.y*bv.y; acc[1][2]+=av.y*bv.z; acc[1][3]+=av.y*bv.w;
        acc[2][0]+=av.z*bv.x; acc[2][1]+=av.z*bv.y; acc[2][2]+=av.z*bv.z; acc[2][3]+=av.z*bv.w;
        acc[3][0]+=av.w*bv.x; acc[3][1]+=av.w*bv.y; acc[3][2]+=av.w*bv.z; acc[3][3]+=av.w*bv.w;
      }
      __syncthreads();
    }
  }
  #pragma unroll
  for (int i = 0; i < 4; ++i){
    int l = l0 + (ty<<2) + i;
    #pragma unroll
    for (int j = 0; j < 4; ++j){
      int n = n0 + (tx<<2) + j;
      if (n < N){
        float v = sc[n]*acc[i][j] + sh[n];
        if (mode == 0){
          out0[((size_t)(b*N + n))*256 + l] = tanhf(v);
        } else {
          size_t ob = ((size_t)b*256 + l)*80 + n;
          after[ob] = before[ob] + v;
        }
      }
    }
  }
}

extern "C" void kernel_launch(void* const* d_in, const int* in_sizes, int n_in,
                              void* d_out, int out_size, void* d_ws, size_t ws_size,
                              hipStream_t stream) {
  Args A;
  A.enc_z = (const float*)d_in[0];  A.ys = (const float*)d_in[1];
  A.ilens = (const int*)d_in[3];
  A.W_enc = (const float*)d_in[4];  A.b_enc = (const float*)d_in[5];
  A.W_dec = (const float*)d_in[6];  A.loc_kernel = (const float*)d_in[7];
  A.W_att = (const float*)d_in[8];  A.g_w = (const float*)d_in[9];  A.g_b = (const float*)d_in[10];
  A.Wp0 = (const float*)d_in[11];   A.bp0 = (const float*)d_in[12];
  A.Wp1 = (const float*)d_in[13];   A.bp1 = (const float*)d_in[14];
  A.Wih0 = (const float*)d_in[15];  A.Whh0 = (const float*)d_in[16];
  A.bih0 = (const float*)d_in[17];  A.bhh0 = (const float*)d_in[18];
  A.Wih1 = (const float*)d_in[19];  A.Whh1 = (const float*)d_in[20];
  A.bih1 = (const float*)d_in[21];  A.bhh1 = (const float*)d_in[22];
  A.Wf = (const float*)d_in[23];    A.bf = (const float*)d_in[24];
  A.Wq = (const float*)d_in[25];    A.bq = (const float*)d_in[26];
  A.pk0 = (const float*)d_in[27];   A.pb0 = (const float*)d_in[28];
  A.bg0 = (const float*)d_in[29];   A.bb0 = (const float*)d_in[30];
  A.pk1 = (const float*)d_in[31];   A.pb1 = (const float*)d_in[32];
  A.bg1 = (const float*)d_in[33];   A.bb1 = (const float*)d_in[34];
  A.pk2 = (const float*)d_in[35];   A.pb2 = (const float*)d_in[36];
  A.bg2 = (const float*)d_in[37];   A.bb2 = (const float*)d_in[38];

  float* ws = (float*)d_ws;
  size_t off = 0;
  auto alloc = [&](size_t n){ float* p = ws + off; off += n; return p; };
  A.enc_proj   = alloc(1048576);
  A.pre_tmp    = alloc(2097152);
  A.pre_all    = alloc(2097152);
  A.G          = alloc(3968);
  A.aw0        = alloc(8192);
  A.p_buf      = alloc(8192);
  A.sum_buf    = alloc(32);
  A.dec        = alloc(4096);
  A.att_c      = alloc(16384);
  A.z0         = alloc(16384);
  A.c0         = alloc(16384);
  A.z1a        = alloc(16384);
  A.z1b        = alloc(16384);
  A.c1         = alloc(16384);
  A.gates_part = alloc(65536);
  A.bias0      = alloc(2048);
  A.bias1      = alloc(2048);
  A.part0      = alloc(262144);
  A.part1      = alloc(262144);
  A.part2      = alloc(262144);
  A.before_t   = alloc(655360);
  A.h0         = alloc(4194304);
  A.h1         = alloc(4194304);
  A.Wt0        = alloc(204800);
  A.Wt1        = alloc(1310720);
  A.Wt2        = alloc(204800);
  A.s0 = alloc(512); A.t0s = alloc(512);
  A.s1 = alloc(512); A.t1s = alloc(512);
  A.s2 = alloc(128); A.t2s = alloc(128);
  A.cnt = (int*)(ws + off); off += 16;

  float* out = (float*)d_out;
  A.out_after  = out;
  A.out_before = out + 655360;
  A.out_logits = out + 1310720;
  A.out_aws    = out + 1318912;

  k_init<<<dim3(512), dim3(256), 0, stream>>>(A);
  k_encproj<<<dim3(256), dim3(256), 0, stream>>>(A);
  k_pre0<<<dim3(256), dim3(256), 0, stream>>>(A);
  k_pre1<<<dim3(256), dim3(256), 0, stream>>>(A);
  k_scan<<<dim3(NBLK), dim3(256), 0, stream>>>(A);
  k_conv<<<dim3(128,8), dim3(256), 0, stream>>>(A.before_t, A.Wt0, A.s0, A.t0s, A.h0, nullptr, nullptr, 80, 512, 0);
  k_conv<<<dim3(128,8), dim3(256), 0, stream>>>(A.h0, A.Wt1, A.s1, A.t1s, A.h1, nullptr, nullptr, 512, 512, 0);
  k_conv<<<dim3(128,2), dim3(256), 0, stream>>>(A.h1, A.Wt2, A.s2, A.t2s, nullptr, A.out_before, A.out_after, 512, 80, 1);
}

// Round 2
// 174654.272 us; speedup vs baseline: 1.1359x; 1.1359x over previous
//
#include <hip/hip_runtime.h>
#include <cstdint>

#define BB 32
#define TT 256
#define LSEQ 256
#define NBLK 256
#define BN_INV 0.99999500003750f

typedef float v4f __attribute__((ext_vector_type(4)));

struct Args {
  const float *enc_z, *ys;
  const int* ilens;
  const float *W_enc, *b_enc, *W_dec, *loc_kernel, *W_att, *g_w, *g_b;
  const float *Wp0, *bp0, *Wp1, *bp1;
  const float *Wih0, *Whh0, *bih0, *bhh0, *Wih1, *Whh1, *bih1, *bhh1;
  const float *Wf, *bf, *Wq, *bq;
  const float *pk0,*pb0,*bg0,*bb0,*pk1,*pb1,*bg1,*bb1,*pk2,*pb2,*bg2,*bb2;
  float *enc_proj, *pre_tmp, *pre_all, *G, *aw0, *p_buf, *sum_buf, *dec, *att_c;
  float *z0, *z0loc, *c0, *z1gA, *z1gB, *z1loc, *c1;
  float *gpre0, *gpre1, *biasP0, *biasP1;
  float *before_t, *h0, *h1, *Wt0, *Wt1, *Wt2, *s0, *t0s, *s1, *t1s, *s2, *t2s;
  int* bar;
  float *out_after, *out_before, *out_logits, *out_aws;
};

__device__ __forceinline__ float sigf(float x){ return 1.0f/(1.0f+expf(-x)); }

// ---- LLC-coherent (cross-XCD) access helpers: sc0 sc1 bypass L1/L2 ----
__device__ __forceinline__ float ldc(const float* p){
  float v;
  asm volatile("global_load_dword %0, %1, off sc0 sc1\n\ts_waitcnt vmcnt(0)"
               : "=v"(v) : "v"(p) : "memory");
  return v;
}
__device__ __forceinline__ v4f ldc4(const float* p){
  v4f v;
  asm volatile("global_load_dwordx4 %0, %1, off sc0 sc1\n\ts_waitcnt vmcnt(0)"
               : "=v"(v) : "v"(p) : "memory");
  return v;
}
__device__ __forceinline__ v4f ldc4_nw(const float* p){
  v4f v;
  asm volatile("global_load_dwordx4 %0, %1, off sc0 sc1"
               : "=v"(v) : "v"(p) : "memory");
  return v;
}
__device__ __forceinline__ void waitvm2(v4f& a, v4f& b){
  asm volatile("s_waitcnt vmcnt(0)" : "+v"(a), "+v"(b) :: "memory");
}
__device__ __forceinline__ void waitvm4(v4f& a, v4f& b, v4f& c, v4f& d){
  asm volatile("s_waitcnt vmcnt(0)" : "+v"(a), "+v"(b), "+v"(c), "+v"(d) :: "memory");
}
__device__ __forceinline__ void stc(float* p, float v){
  asm volatile("global_store_dword %0, %1, off sc0 sc1" :: "v"(p), "v"(v) : "memory");
}
__device__ __forceinline__ int ldci(const int* p){
  int v;
  asm volatile("global_load_dword %0, %1, off sc0 sc1\n\ts_waitcnt vmcnt(0)"
               : "=v"(v) : "v"(p) : "memory");
  return v;
}
__device__ __forceinline__ void stci(int* p, int v){
  asm volatile("global_store_dword %0, %1, off sc0 sc1" :: "v"(p), "v"(v) : "memory");
}
__device__ __forceinline__ void waitvm_all(){
  asm volatile("s_waitcnt vmcnt(0)" ::: "memory");
}

// ---- fence-free tree grid barrier: no buffer_inv / buffer_wbl2 ever ----
// layout (ints, stride 64 = 256B): grp[0..7] at g*64, root at 8*64, done[g] at (9+g)*64
__device__ __forceinline__ void gbar(int* bar, int round, int blk){
  waitvm_all();           // every wave drains its own coherent stores to LLC
  __syncthreads();
  if (threadIdx.x == 0){
    int g = blk >> 5;
    atomicAdd(bar + g*64, 1);
    if ((blk & 31) == 0){
      while (ldci(bar + g*64) < round*32) __builtin_amdgcn_s_sleep(1);
      atomicAdd(bar + 8*64, 1);
      while (ldci(bar + 8*64) < round*8) __builtin_amdgcn_s_sleep(1);
      stci(bar + (9+g)*64, round);
    } else {
      while (ldci(bar + (9+g)*64) < round) __builtin_amdgcn_s_sleep(2);
    }
  }
  __syncthreads();
}

// ---------------- init: small precomputes ----------------
__global__ void k_init(Args A){
  int tid0 = blockIdx.x*blockDim.x + threadIdx.x;
  int stride = gridDim.x*blockDim.x;
  for (int i = tid0; i < 31*128; i += stride){
    int k = i >> 7, d = i & 127;
    float s = 0.f;
    for (int c = 0; c < 32; ++c) s += A.W_att[c*128+d]*A.loc_kernel[c*31+k];
    A.G[i] = s;
  }
  // packed biases: biasP[u*4 + gate]
  for (int i = tid0; i < 2048; i += stride){
    int u = i & 511, g = i >> 9;
    A.biasP0[u*4+g] = A.bih0[i]+A.bhh0[i];
    A.biasP1[u*4+g] = A.bih1[i]+A.bhh1[i];
  }
  for (int i = tid0; i < 16384; i += stride){
    A.z0[i]=0.f; A.z0loc[i]=0.f; A.c0[i]=0.f;
    A.z1gA[i]=0.f; A.z1gB[i]=0.f; A.z1loc[i]=0.f; A.c1[i]=0.f;
  }
  for (int i = tid0; i < 65536; i += stride) A.gpre0[i]=0.f;
  for (int i = tid0; i < 4096; i += stride) A.dec[i]=0.f;
  if (tid0 < 32) A.sum_buf[tid0]=0.f;
  for (int i = tid0; i < 1088; i += stride) A.bar[i]=0;
  for (int i = tid0; i < 32*256; i += stride){
    int b = i>>8, t = i&255; int il = A.ilens[b];
    A.aw0[i] = (t < il) ? 1.0f/(float)il : 0.0f;
  }
  for (int i = tid0; i < 512; i += stride){
    float s = A.bg0[i]*BN_INV; A.s0[i]=s; A.t0s[i]=s*A.pb0[i]+A.bb0[i];
    float u = A.bg1[i]*BN_INV; A.s1[i]=u; A.t1s[i]=u*A.pb1[i]+A.bb1[i];
  }
  for (int i = tid0; i < 80; i += stride){
    float s = A.bg2[i]*BN_INV; A.s2[i]=s; A.t2s[i]=s*A.pb2[i]+A.bb2[i];
  }
  for (int i = tid0; i < 5*80*512; i += stride){
    int k = i/(80*512); int r = i - k*(80*512); int c = r>>9, n = r&511;
    A.Wt0[i] = A.pk0[(n*80+c)*5+k];
  }
  for (int i = tid0; i < 5*512*512; i += stride){
    int k = i/(512*512); int r = i - k*(512*512); int c = r>>9, n = r&511;
    A.Wt1[i] = A.pk1[(n*512+c)*5+k];
  }
  for (int i = tid0; i < 5*512*80; i += stride){
    int k = i/(512*80); int r = i - k*(512*80); int c = r/80, n = r - c*80;
    A.Wt2[i] = A.pk2[(n*512+c)*5+k];
  }
}

// ---------------- enc_proj = enc_z @ W_enc + b_enc ----------------
__global__ void __launch_bounds__(256) k_encproj(Args A){
  __shared__ __align__(16) float As[32][128];
  int m0 = blockIdx.x*32;
  int tid = threadIdx.x;
  int d = tid & 127, half = tid >> 7;
  float acc[16];
  #pragma unroll
  for (int r = 0; r < 16; ++r) acc[r] = 0.f;
  for (int j0 = 0; j0 < 512; j0 += 128){
    for (int i = 0; i < 16; ++i){
      int e = tid + i*256; int r = e >> 7, j = e & 127;
      As[r][j] = A.enc_z[(size_t)(m0+r)*512 + j0 + j];
    }
    __syncthreads();
    for (int j = 0; j < 128; ++j){
      float w = A.W_enc[(size_t)(j0+j)*128 + d];
      #pragma unroll
      for (int r = 0; r < 16; ++r) acc[r] += As[half*16+r][j]*w;
    }
    __syncthreads();
  }
  float be = A.b_enc[d];
  for (int r = 0; r < 16; ++r)
    A.enc_proj[(size_t)(m0+half*16+r)*128 + d] = acc[r] + be;
}

// ---------------- prenet ----------------
__global__ void __launch_bounds__(256) k_pre0(Args A){
  __shared__ float As[32][80];
  int m0 = blockIdx.x*32, tid = threadIdx.x;
  for (int e = tid; e < 2560; e += 256){
    int r = e/80, o = e - r*80;
    int row = m0+r; int l = row & 255, b = row >> 8;
    As[r][o] = (l==0) ? 0.f : A.ys[((size_t)b*256 + (l-1))*80 + o];
  }
  __syncthreads();
  float acc[32];
  #pragma unroll
  for (int r = 0; r < 32; ++r) acc[r] = 0.f;
  for (int o = 0; o < 80; ++o){
    float w = A.Wp0[o*256 + tid];
    #pragma unroll
    for (int r = 0; r < 32; ++r) acc[r] += As[r][o]*w;
  }
  float bb = A.bp0[tid];
  for (int r = 0; r < 32; ++r){
    float v = acc[r]+bb;
    A.pre_tmp[(size_t)(m0+r)*256 + tid] = v>0.f?v:0.f;
  }
}

__global__ void __launch_bounds__(256) k_pre1(Args A){
  __shared__ float As[32][256];
  int m0 = blockIdx.x*32, tid = threadIdx.x;
  for (int e = tid; e < 8192; e += 256){
    int r = e >> 8, j = e & 255;
    As[r][j] = A.pre_tmp[(size_t)(m0+r)*256 + j];
  }
  __syncthreads();
  float acc[32];
  #pragma unroll
  for (int r = 0; r < 32; ++r) acc[r] = 0.f;
  for (int j = 0; j < 256; ++j){
    float w = A.Wp1[j*256 + tid];
    #pragma unroll
    for (int r = 0; r < 32; ++r) acc[r] += As[r][j]*w;
  }
  float bb = A.bp1[tid];
  for (int r = 0; r < 32; ++r){
    float v = acc[r]+bb;
    A.pre_all[(size_t)(m0+r)*256 + tid] = v>0.f?v:0.f;
  }
}

// one K=256 slice of a 32-row x (4 cols/thread) gemm; X staged in LDS.
// thread's 4 cols = col..col+3; acc accumulated in-place. COH: X is LLC-coherent.
template<bool COH>
__device__ __forceinline__ void gemm_slice(const float* __restrict__ W,
    const float* __restrict__ Xg, size_t xstride, int col,
    v4f& acc, float* __restrict__ Xlds, int tid)
{
  const int pitch = 260;
  v4f t0,t1,t2,t3,t4,t5,t6,t7;
  #define LDX(i, dst) { int f=tid+((i)<<8); int b=f>>6; int j=(f&63)<<2; \
      const float* p = Xg + (size_t)b*xstride + j; \
      if (COH) dst = ldc4_nw(p); else dst = *(const v4f*)p; }
  LDX(0,t0) LDX(1,t1) LDX(2,t2) LDX(3,t3) LDX(4,t4) LDX(5,t5) LDX(6,t6) LDX(7,t7)
  #undef LDX
  if (COH){ waitvm4(t0,t1,t2,t3); waitvm4(t4,t5,t6,t7); }
  #define STX(i, src) { int f=tid+((i)<<8); int b=f>>6; int j=(f&63)<<2; \
      *(v4f*)&Xlds[b*pitch+j] = src; }
  STX(0,t0) STX(1,t1) STX(2,t2) STX(3,t3) STX(4,t4) STX(5,t5) STX(6,t6) STX(7,t7)
  #undef STX
  __syncthreads();
  const float* xr = Xlds + (tid>>3)*pitch;
  const float* wc = W + col;
  float ax=acc.x, ay=acc.y, az=acc.z, aw=acc.w;
  #pragma unroll 8
  for (int j = 0; j < 256; ++j){
    float x = xr[j];
    const v4f w = *reinterpret_cast<const v4f*>(wc + (size_t)j*2048);
    ax += x*w.x; ay += x*w.y; az += x*w.z; aw += x*w.w;
  }
  acc.x=ax; acc.y=ay; acc.z=az; acc.w=aw;
  __syncthreads();
}

// store 4 cols' results packed as P[b*2048 + unit*4 + gate] (coherent)
__device__ __forceinline__ void store_packed(float* P, int b, int col, const v4f& a){
  int g = col >> 9, u = col & 511;
  float* p0 = P + b*2048 + u*4 + g;
  stc(p0+0, a.x); stc(p0+4, a.y); stc(p0+8, a.z); stc(p0+12, a.w);
}

// ---------------- the scan ----------------
__global__ void __launch_bounds__(256) k_scan(Args A){
  __shared__ __align__(16) float Gs[3968];
  __shared__ __align__(16) float S[8320];   // 32x260 staging / misc
  const int blk = blockIdx.x, tid = threadIdx.x;
  int rnd = 0;
  #define GBAR() gbar(A.bar, ++rnd, blk)

  for (int e = tid; e < 3968; e += 256) Gs[e] = A.G[e];

  // Ph0: gpre1(0) = pre(0) @ Wih0[512:768]  (blocks 128..191)
  if (blk >= 128 && blk < 192){
    int chunk = blk - 128, col = chunk*32 + (tid&7)*4, b = tid>>3;
    v4f acc = {0.f,0.f,0.f,0.f};
    gemm_slice<false>(A.Wih0 + (size_t)512*2048, A.pre_all, 65536, col, acc, S, tid);
    store_packed(A.gpre1, b, col, acc);
  }
  GBAR();

  for (int t = 0; t < LSEQ; ++t){
    const float* z1rd = (t&1) ? A.z1gB : A.z1gA;
    float*       z1wr = (t&1) ? A.z1gA : A.z1gB;

    // ---- Ph1: attention e -> p=exp(2e), per-b sums; out/logit for t-1 ----
    {
      int b = blk>>3, t0 = (blk&7)*32;
      const float* awp = (t==0) ? (A.aw0 + b*256)
                                : (A.out_aws + ((size_t)b*256 + (t-1))*256);
      float* awin = S;        // 64
      float* decs = S + 64;   // 128
      float* gws  = S + 192;  // 128
      float* psum = S + 320;  // 32
      float* z1s  = S + 384;  // 512
      float* acs  = S + 896;  // 512
      if (tid < 128) decs[tid] = ldc(A.dec + b*128 + tid);
      else           gws[tid-128] = A.g_w[tid-128];
      if (tid < 62){ int ix = t0 - 15 + tid; awin[tid] = ((unsigned)ix < 256u) ? ldc(awp + ix) : 0.f; }
      bool outblk = ((blk&7)==7) && (t > 0);
      if (outblk){
        if (tid < 128) *(v4f*)&z1s[tid*4] = ldc4(z1rd + b*512 + tid*4);
        else           *(v4f*)&acs[(tid-128)*4] = ldc4(A.att_c + b*512 + (tid-128)*4);
      }
      __syncthreads();
      int lane = tid & 7, tl = tid >> 3;
      int tt = t0 + tl, d0 = lane*16;
      float att[16];
      #pragma unroll
      for (int i = 0; i < 16; ++i) att[i] = 0.f;
      for (int k = 0; k < 31; ++k){
        float a = awin[tl + k];
        const float* gp = &Gs[k*128 + d0];
        #pragma unroll
        for (int i = 0; i < 16; ++i) att[i] += gp[i]*a;
      }
      const float* ep = A.enc_proj + ((size_t)b*256 + tt)*128 + d0;
      float part = 0.f;
      #pragma unroll
      for (int i = 0; i < 16; ++i){
        float v = att[i] + ep[i] + decs[d0+i];
        part += tanhf(v)*gws[d0+i];
      }
      part += __shfl_xor(part,1); part += __shfl_xor(part,2); part += __shfl_xor(part,4);
      if (lane == 0){
        float e = part + A.g_b[0];
        float p = (tt < A.ilens[b]) ? expf(2.0f*e) : 0.0f;
        stc(A.p_buf + b*256 + tt, p);
        psum[tl] = p;
      }
      __syncthreads();
      if (tid == 0){
        float ssum = 0.f;
        for (int i = 0; i < 32; ++i) ssum += psum[i];
        atomicAdd(A.sum_buf + b, ssum);
      }
      if (outblk && tid <= 80){
        bool iso = tid < 80;
        int st = iso ? 80 : 1;
        const float* Wv = iso ? (A.Wf + tid) : A.Wq;
        float acc = iso ? A.bf[tid] : A.bq[0];
        for (int j = 0; j < 512; ++j) acc += z1s[j]*Wv[(size_t)j*st];
        for (int j = 0; j < 512; ++j) acc += acs[j]*Wv[(size_t)(512+j)*st];
        int to = t-1;
        if (iso){
          A.out_before[((size_t)b*256 + to)*80 + tid] = acc;
          A.before_t[((size_t)b*80 + tid)*256 + to] = acc;
        } else {
          A.out_logits[(size_t)b*256 + to] = acc;
        }
      }
    }
    GBAR();

    // ---- Ph2: att_c = (p @ enc_z)/sum ; normalized aw out ----
    {
      int b = blk>>3, chunk = blk&7;
      int dd = tid & 63, g = tid >> 6;
      int d = chunk*64 + dd;
      float inv = 1.0f / ldc(A.sum_buf + b);
      float* Sp  = S;        // 256
      float* red = S + 256;  // 256
      Sp[tid] = ldc(A.p_buf + b*256 + tid);
      __syncthreads();
      const float* ez = A.enc_z + ((size_t)b*256)*512 + d;
      float partial = 0.f;
      for (int q = g*64; q < g*64+64; ++q) partial += Sp[q]*ez[(size_t)q*512];
      red[g*64 + dd] = partial;
      __syncthreads();
      if (g == 0){
        float v = red[dd] + red[64+dd] + red[128+dd] + red[192+dd];
        stc(A.att_c + b*512 + d, v*inv);
      }
      if (chunk == 0) stc(A.out_aws + ((size_t)b*256 + t)*256 + tid, Sp[tid]*inv);
    }
    GBAR();

    // ---- Ph3: LSTM0 gates (att part) + finalize (blocks 0..63, 8 units each) ----
    if (blk < 64){
      int sub = tid & 7, g = sub >> 1, qsel = sub & 1;
      int col = blk*8 + qsel*4 + 512*g;
      v4f acc = {0.f,0.f,0.f,0.f};
      gemm_slice<true>(A.Wih0,                     A.att_c,       512, col, acc, S, tid);
      gemm_slice<true>(A.Wih0 + (size_t)256*2048,  A.att_c + 256, 512, col, acc, S, tid);
      float* Sg = S;   // 32 x 33 transpose buffer (reuse staging)
      {
        int b = tid>>3;
        float* q = &Sg[b*33 + sub*4];
        q[0]=acc.x; q[1]=acc.y; q[2]=acc.z; q[3]=acc.w;
      }
      __syncthreads();
      int lu = tid & 7, b2 = tid >> 3;
      int u = blk*8 + lu;
      v4f pA = ldc4_nw(A.gpre0 + b2*2048 + u*4);
      v4f pB = ldc4_nw(A.gpre1 + b2*2048 + u*4);
      waitvm2(pA, pB);
      const v4f bs = *(const v4f*)&A.biasP0[u*4];
      float gi = Sg[b2*33 + ((lu>>2)    )*4 + (lu&3)] + pA.x + pB.x + bs.x;
      float gf = Sg[b2*33 + (2+(lu>>2)  )*4 + (lu&3)] + pA.y + pB.y + bs.y;
      float gg = Sg[b2*33 + (4+(lu>>2)  )*4 + (lu&3)] + pA.z + pB.z + bs.z;
      float go = Sg[b2*33 + (6+(lu>>2)  )*4 + (lu&3)] + pA.w + pB.w + bs.w;
      float c_old = A.c0[b2*512+u], z_old = A.z0loc[b2*512+u];
      float c2 = sigf(gf)*c_old + sigf(gi)*tanhf(gg);
      float h  = sigf(go)*tanhf(c2);
      float cn = 0.1f*c_old + 0.9f*c2;
      float zn = 0.1f*z_old + 0.9f*h;
      A.c0[b2*512+u] = cn;
      A.z0loc[b2*512+u] = zn;
      stc(A.z0 + b2*512 + u, zn);
    }
    GBAR();

    // ---- Ph4: LSTM1 gates+finalize; gpre0/gpre1 prefetch; dec(t+1); sum reset ----
    if (blk < 64){
      int sub = tid & 7, g = sub >> 1, qsel = sub & 1;
      int col = blk*8 + qsel*4 + 512*g;
      v4f acc = {0.f,0.f,0.f,0.f};
      gemm_slice<true>(A.Wih1,                    A.z0,        512, col, acc, S, tid);
      gemm_slice<true>(A.Wih1 + (size_t)256*2048, A.z0 + 256,  512, col, acc, S, tid);
      gemm_slice<true>(A.Whh1,                    z1rd,        512, col, acc, S, tid);
      gemm_slice<true>(A.Whh1 + (size_t)256*2048, z1rd + 256,  512, col, acc, S, tid);
      float* Sg = S;
      {
        int b = tid>>3;
        float* q = &Sg[b*33 + sub*4];
        q[0]=acc.x; q[1]=acc.y; q[2]=acc.z; q[3]=acc.w;
      }
      __syncthreads();
      int lu = tid & 7, b2 = tid >> 3;
      int u = blk*8 + lu;
      const v4f bs = *(const v4f*)&A.biasP1[u*4];
      float gi = Sg[b2*33 + ((lu>>2)  )*4 + (lu&3)] + bs.x;
      float gf = Sg[b2*33 + (2+(lu>>2))*4 + (lu&3)] + bs.y;
      float gg = Sg[b2*33 + (4+(lu>>2))*4 + (lu&3)] + bs.z;
      float go = Sg[b2*33 + (6+(lu>>2))*4 + (lu&3)] + bs.w;
      float c_old = A.c1[b2*512+u], z_old = A.z1loc[b2*512+u];
      float c2 = sigf(gf)*c_old + sigf(gi)*tanhf(gg);
      float h  = sigf(go)*tanhf(c2);
      float cn = 0.1f*c_old + 0.9f*c2;
      float zn = 0.1f*z_old + 0.9f*h;
      A.c1[b2*512+u] = cn;
      A.z1loc[b2*512+u] = zn;
      stc(z1wr + b2*512 + u, zn);
    } else if (blk < 128){
      if (t < 255){
        int chunk = blk - 64, col = chunk*32 + (tid&7)*4, b = tid>>3;
        v4f acc = {0.f,0.f,0.f,0.f};
        gemm_slice<true>(A.Whh0,                    A.z0,       512, col, acc, S, tid);
        gemm_slice<true>(A.Whh0 + (size_t)256*2048, A.z0 + 256, 512, col, acc, S, tid);
        store_packed(A.gpre0, b, col, acc);
      }
    } else if (blk < 192){
      if (t < 255){
        int chunk = blk - 128, col = chunk*32 + (tid&7)*4, b = tid>>3;
        v4f acc = {0.f,0.f,0.f,0.f};
        gemm_slice<false>(A.Wih0 + (size_t)512*2048,
                          A.pre_all + (size_t)(t+1)*256, 65536, col, acc, S, tid);
        store_packed(A.gpre1, b, col, acc);
      }
    } else if (blk < 224){
      if (t < 255){
        int b = blk - 192;
        float* zs = S;
        if (tid < 128) *(v4f*)&zs[tid*4] = ldc4(A.z0 + b*512 + tid*4);
        __syncthreads();
        if (tid < 128){
          float dv = 0.f;
          for (int j = 0; j < 512; ++j) dv += zs[j]*A.W_dec[j*128 + tid];
          stc(A.dec + b*128 + tid, dv);
        }
      }
    } else if (blk == 224){
      if (tid < 32) stc(A.sum_buf + tid, 0.f);
    }
    GBAR();
  }

  // tail: out/logit for t=255 (z1(255) is in z1gA since t=255 is odd -> wr=A)
  if (blk < 32){
    int b = blk;
    float* z1s = S;       // 512
    float* acs = S + 512; // 512
    if (tid < 128) *(v4f*)&z1s[tid*4] = ldc4(A.z1gA + b*512 + tid*4);
    else           *(v4f*)&acs[(tid-128)*4] = ldc4(A.att_c + b*512 + (tid-128)*4);
    __syncthreads();
    if (tid <= 80){
      bool iso = tid < 80;
      int st = iso ? 80 : 1;
      const float* Wv = iso ? (A.Wf + tid) : A.Wq;
      float acc = iso ? A.bf[tid] : A.bq[0];
      for (int j = 0; j < 512; ++j) acc += z1s[j]*Wv[(size_t)j*st];
      for (int j = 0; j < 512; ++j) acc += acs[j]*Wv[(size_t)(512+j)*st];
      if (iso){
        A.out_before[((size_t)b*256 + 255)*80 + tid] = acc;
        A.before_t[((size_t)b*80 + tid)*256 + 255] = acc;
      } else {
        A.out_logits[(size_t)b*256 + 255] = acc;
      }
    }
  }
  #undef GBAR
}

// ---------------- postnet conv (kernel=5, pad=2) as tiled GEMM ----------------
__global__ void __launch_bounds__(256) k_conv(const float* __restrict__ in,
                       const float* __restrict__ Wt,  // (5, C, N)
                       const float* __restrict__ sc, const float* __restrict__ sh,
                       float* __restrict__ out0, const float* __restrict__ before,
                       float* __restrict__ after, int C, int N, int mode)
{
  __shared__ __align__(16) float As[16][64];
  __shared__ __align__(16) float Bs[16][64];
  int bx = blockIdx.x;
  int b = bx >> 2, l0 = (bx & 3)*64;
  int n0 = blockIdx.y*64;
  int tid = threadIdx.x, tx = tid & 15, ty = tid >> 4;
  float acc[4][4];
  #pragma unroll
  for (int i = 0; i < 4; ++i)
    #pragma unroll
    for (int j = 0; j < 4; ++j) acc[i][j] = 0.f;
  for (int k = 0; k < 5; ++k){
    int shift = k - 2;
    for (int c0 = 0; c0 < C; c0 += 16){
      #pragma unroll
      for (int i = 0; i < 4; ++i){
        int e = tid + i*256; int cc = e >> 6, ll = e & 63;
        int l = l0 + ll + shift;
        As[cc][ll] = ((unsigned)l < 256u) ? in[((size_t)(b*C + c0+cc))*256 + l] : 0.f;
        int n = n0 + ll;
        Bs[cc][ll] = (n < N) ? Wt[((size_t)k*C + c0+cc)*(size_t)N + n] : 0.f;
      }
      __syncthreads();
      #pragma unroll
      for (int cc = 0; cc < 16; ++cc){
        const float4 av = *reinterpret_cast<const float4*>(&As[cc][ty<<2]);
        const float4 bv = *reinterpret_cast<const float4*>(&Bs[cc][tx<<2]);
        acc[0][0]+=av.x*bv.x; acc[0][1]+=av.x*bv.y; acc[0][2]+=av.x*bv.z; acc[0][3]+=av.x*bv.w;
        acc[1][0]+=av.y*bv.x; acc[1][1]+=av.y*bv.y; acc[1][2]+=av.y*bv.z; acc[1][3]+=av.y*bv.w;
        acc[2][0]+=av.z*bv.x; acc[2][1]+=av.z*bv.y; acc[2][2]+=av.z*bv.z; acc[2][3]+=av.z*bv.w;
        acc[3][0]+=av.w*bv.x; acc[3][1]+=av.w*bv.y; acc[3][2]+=av.w*bv.z; acc[3][3]+=av.w*bv.w;
      }
      __syncthreads();
    }
  }
  #pragma unroll
  for (int i = 0; i < 4; ++i){
    int l = l0 + (ty<<2) + i;
    #pragma unroll
    for (int j = 0; j < 4; ++j){
      int n = n0 + (tx<<2) + j;
      if (n < N){
        float v = sc[n]*acc[i][j] + sh[n];
        if (mode == 0){
          out0[((size_t)(b*N + n))*256 + l] = tanhf(v);
        } else {
          size_t ob = ((size_t)b*256 + l)*80 + n;
          after[ob] = before[ob] + v;
        }
      }
    }
  }
}

extern "C" void kernel_launch(void* const* d_in, const int* in_sizes, int n_in,
                              void* d_out, int out_size, void* d_ws, size_t ws_size,
                              hipStream_t stream) {
  Args A;
  A.enc_z = (const float*)d_in[0];  A.ys = (const float*)d_in[1];
  A.ilens = (const int*)d_in[3];
  A.W_enc = (const float*)d_in[4];  A.b_enc = (const float*)d_in[5];
  A.W_dec = (const float*)d_in[6];  A.loc_kernel = (const float*)d_in[7];
  A.W_att = (const float*)d_in[8];  A.g_w = (const float*)d_in[9];  A.g_b = (const float*)d_in[10];
  A.Wp0 = (const float*)d_in[11];   A.bp0 = (const float*)d_in[12];
  A.Wp1 = (const float*)d_in[13];   A.bp1 = (const float*)d_in[14];
  A.Wih0 = (const float*)d_in[15];  A.Whh0 = (const float*)d_in[16];
  A.bih0 = (const float*)d_in[17];  A.bhh0 = (const float*)d_in[18];
  A.Wih1 = (const float*)d_in[19];  A.Whh1 = (const float*)d_in[20];
  A.bih1 = (const float*)d_in[21];  A.bhh1 = (const float*)d_in[22];
  A.Wf = (const float*)d_in[23];    A.bf = (const float*)d_in[24];
  A.Wq = (const float*)d_in[25];    A.bq = (const float*)d_in[26];
  A.pk0 = (const float*)d_in[27];   A.pb0 = (const float*)d_in[28];
  A.bg0 = (const float*)d_in[29];   A.bb0 = (const float*)d_in[30];
  A.pk1 = (const float*)d_in[31];   A.pb1 = (const float*)d_in[32];
  A.bg1 = (const float*)d_in[33];   A.bb1 = (const float*)d_in[34];
  A.pk2 = (const float*)d_in[35];   A.pb2 = (const float*)d_in[36];
  A.bg2 = (const float*)d_in[37];   A.bb2 = (const float*)d_in[38];

  float* ws = (float*)d_ws;
  size_t off = 0;
  auto alloc = [&](size_t n){ float* p = ws + off; off += n; return p; };
  A.enc_proj   = alloc(1048576);
  A.pre_tmp    = alloc(2097152);
  A.pre_all    = alloc(2097152);
  A.G          = alloc(3968);
  A.aw0        = alloc(8192);
  A.p_buf      = alloc(8192);
  A.sum_buf    = alloc(32);
  A.dec        = alloc(4096);
  A.att_c      = alloc(16384);
  A.z0         = alloc(16384);
  A.z0loc      = alloc(16384);
  A.c0         = alloc(16384);
  A.z1gA       = alloc(16384);
  A.z1gB       = alloc(16384);
  A.z1loc      = alloc(16384);
  A.c1         = alloc(16384);
  A.gpre0      = alloc(65536);
  A.gpre1      = alloc(65536);
  A.biasP0     = alloc(2048);
  A.biasP1     = alloc(2048);
  A.before_t   = alloc(655360);
  A.h0         = alloc(4194304);
  A.h1         = alloc(4194304);
  A.Wt0        = alloc(204800);
  A.Wt1        = alloc(1310720);
  A.Wt2        = alloc(204800);
  A.s0 = alloc(512); A.t0s = alloc(512);
  A.s1 = alloc(512); A.t1s = alloc(512);
  A.s2 = alloc(128); A.t2s = alloc(128);
  A.bar = (int*)(ws + off); off += 1088;

  float* out = (float*)d_out;
  A.out_after  = out;
  A.out_before = out + 655360;
  A.out_logits = out + 1310720;
  A.out_aws    = out + 1318912;

  k_init<<<dim3(512), dim3(256), 0, stream>>>(A);
  k_encproj<<<dim3(256), dim3(256), 0, stream>>>(A);
  k_pre0<<<dim3(256), dim3(256), 0, stream>>>(A);
  k_pre1<<<dim3(256), dim3(256), 0, stream>>>(A);
  k_scan<<<dim3(NBLK), dim3(256), 0, stream>>>(A);
  k_conv<<<dim3(128,8), dim3(256), 0, stream>>>(A.before_t, A.Wt0, A.s0, A.t0s, A.h0, nullptr, nullptr, 80, 512, 0);
  k_conv<<<dim3(128,8), dim3(256), 0, stream>>>(A.h0, A.Wt1, A.s1, A.t1s, A.h1, nullptr, nullptr, 512, 512, 0);
  k_conv<<<dim3(128,2), dim3(256), 0, stream>>>(A.h1, A.Wt2, A.s2, A.t2s, nullptr, A.out_before, A.out_after, 512, 80, 1);
}

// Round 3
// 33988.937 us; speedup vs baseline: 5.8371x; 5.1386x over previous
//
#include <hip/hip_runtime.h>
#include <cstdint>

#define LSEQ 256
#define NBLK 256
#define BN_INV 0.99999500003750f
#define DYN_LDS_BYTES 148480   // 37120 floats

typedef float v4f __attribute__((ext_vector_type(4)));

struct Args {
  const float *enc_z, *ys;
  const int* ilens;
  const float *W_enc, *b_enc, *W_dec, *loc_kernel, *W_att, *g_w, *g_b;
  const float *Wp0, *bp0, *Wp1, *bp1;
  const float *Wih0, *Whh0, *bih0, *bhh0, *Wih1, *Whh1, *bih1, *bhh1;
  const float *Wf, *bf, *Wq, *bq;
  const float *pk0,*pb0,*bg0,*bb0,*pk1,*pb1,*bg1,*bb1,*pk2,*pb2,*bg2,*bb2;
  float *enc_proj, *pre_tmp, *pre_all, *G, *aw0, *p_buf, *psums, *dec, *att_c;
  float *z0, *z1buf, *G0a, *G1a, *G1b, *gpre0, *gpre1, *biasP0, *biasP1;
  float *before_t, *h0, *h1, *Wt0, *Wt1, *Wt2, *s0, *t0s, *s1, *t1s, *s2, *t2s;
  int* bar;
  float *out_after, *out_before, *out_logits, *out_aws;
};

__device__ __forceinline__ float sigf(float x){ return 1.0f/(1.0f+expf(-x)); }

// ---- LLC-coherent access helpers (cross-XCD; bypass L1/L2 via sc0 sc1) ----
__device__ __forceinline__ float ldc(const float* p){
  float v;
  asm volatile("global_load_dword %0, %1, off sc0 sc1\n\ts_waitcnt vmcnt(0)"
               : "=v"(v) : "v"(p) : "memory");
  return v;
}
__device__ __forceinline__ v4f ldc4(const float* p){
  v4f v;
  asm volatile("global_load_dwordx4 %0, %1, off sc0 sc1\n\ts_waitcnt vmcnt(0)"
               : "=v"(v) : "v"(p) : "memory");
  return v;
}
__device__ __forceinline__ v4f ldc4_nw(const float* p){
  v4f v;
  asm volatile("global_load_dwordx4 %0, %1, off sc0 sc1"
               : "=v"(v) : "v"(p) : "memory");
  return v;
}
__device__ __forceinline__ void waitvm2(v4f& a, v4f& b){
  asm volatile("s_waitcnt vmcnt(0)" : "+v"(a), "+v"(b) :: "memory");
}
__device__ __forceinline__ void waitvm4(v4f& a, v4f& b, v4f& c, v4f& d){
  asm volatile("s_waitcnt vmcnt(0)" : "+v"(a), "+v"(b), "+v"(c), "+v"(d) :: "memory");
}
__device__ __forceinline__ void stc(float* p, float v){
  asm volatile("global_store_dword %0, %1, off sc0 sc1" :: "v"(p), "v"(v) : "memory");
}
__device__ __forceinline__ int ldci(const int* p){
  int v;
  asm volatile("global_load_dword %0, %1, off sc0 sc1\n\ts_waitcnt vmcnt(0)"
               : "=v"(v) : "v"(p) : "memory");
  return v;
}
__device__ __forceinline__ void stci(int* p, int v){
  asm volatile("global_store_dword %0, %1, off sc0 sc1" :: "v"(p), "v"(v) : "memory");
}
__device__ __forceinline__ void waitvm_all(){
  asm volatile("s_waitcnt vmcnt(0)" ::: "memory");
}

// ---- flat flag-array grid barrier: arrive[blk] stores, leader gathers, release flag ----
// bar layout (ints): [0..255] arrive, [320] release
__device__ __forceinline__ void gbar(int* bar, int rnd, int blk, int tid){
  waitvm_all();
  __syncthreads();
  if (tid == 0) stci(bar + blk, rnd);
  if (blk == 255){
    int ok;
    do {
      int v = ldci(bar + tid);
      ok = __syncthreads_count(v >= rnd);
      if (ok < 256) __builtin_amdgcn_s_sleep(1);
    } while (ok < 256);
    if (tid == 0) stci(bar + 320, rnd);
    __syncthreads();
  } else {
    if (tid == 0){
      while (ldci(bar + 320) < rnd) __builtin_amdgcn_s_sleep(2);
    }
    __syncthreads();
  }
}

// ---------------- init: small precomputes ----------------
__global__ void k_init(Args A){
  int tid0 = blockIdx.x*blockDim.x + threadIdx.x;
  int stride = gridDim.x*blockDim.x;
  for (int i = tid0; i < 31*128; i += stride){
    int k = i >> 7, d = i & 127;
    float s = 0.f;
    for (int c = 0; c < 32; ++c) s += A.W_att[c*128+d]*A.loc_kernel[c*31+k];
    A.G[i] = s;
  }
  for (int i = tid0; i < 2048; i += stride){
    int u = i & 511, g = i >> 9;
    A.biasP0[u*4+g] = A.bih0[i]+A.bhh0[i];
    A.biasP1[u*4+g] = A.bih1[i]+A.bhh1[i];
  }
  for (int i = tid0; i < 16384; i += stride){ A.z0[i]=0.f; A.z1buf[i]=0.f; }
  for (int i = tid0; i < 65536; i += stride) A.gpre0[i]=0.f;
  for (int i = tid0; i < 4096; i += stride) A.dec[i]=0.f;
  for (int i = tid0; i < 512; i += stride) A.bar[i]=0;
  for (int i = tid0; i < 32*256; i += stride){
    int b = i>>8, t = i&255; int il = A.ilens[b];
    A.aw0[i] = (t < il) ? 1.0f/(float)il : 0.0f;
  }
  for (int i = tid0; i < 512; i += stride){
    float s = A.bg0[i]*BN_INV; A.s0[i]=s; A.t0s[i]=s*A.pb0[i]+A.bb0[i];
    float u = A.bg1[i]*BN_INV; A.s1[i]=u; A.t1s[i]=u*A.pb1[i]+A.bb1[i];
  }
  for (int i = tid0; i < 80; i += stride){
    float s = A.bg2[i]*BN_INV; A.s2[i]=s; A.t2s[i]=s*A.pb2[i]+A.bb2[i];
  }
  for (int i = tid0; i < 5*80*512; i += stride){
    int k = i/(80*512); int r = i - k*(80*512); int c = r>>9, n = r&511;
    A.Wt0[i] = A.pk0[(n*80+c)*5+k];
  }
  for (int i = tid0; i < 5*512*512; i += stride){
    int k = i/(512*512); int r = i - k*(512*512); int c = r>>9, n = r&511;
    A.Wt1[i] = A.pk1[(n*512+c)*5+k];
  }
  for (int i = tid0; i < 5*512*80; i += stride){
    int k = i/(512*80); int r = i - k*(512*80); int c = r/80, n = r - c*80;
    A.Wt2[i] = A.pk2[(n*512+c)*5+k];
  }
}

// ---------------- enc_proj = enc_z @ W_enc + b_enc ----------------
__global__ void __launch_bounds__(256) k_encproj(Args A){
  __shared__ __align__(16) float As[32][128];
  int m0 = blockIdx.x*32;
  int tid = threadIdx.x;
  int d = tid & 127, half = tid >> 7;
  float acc[16];
  #pragma unroll
  for (int r = 0; r < 16; ++r) acc[r] = 0.f;
  for (int j0 = 0; j0 < 512; j0 += 128){
    for (int i = 0; i < 16; ++i){
      int e = tid + i*256; int r = e >> 7, j = e & 127;
      As[r][j] = A.enc_z[(size_t)(m0+r)*512 + j0 + j];
    }
    __syncthreads();
    for (int j = 0; j < 128; ++j){
      float w = A.W_enc[(size_t)(j0+j)*128 + d];
      #pragma unroll
      for (int r = 0; r < 16; ++r) acc[r] += As[half*16+r][j]*w;
    }
    __syncthreads();
  }
  float be = A.b_enc[d];
  for (int r = 0; r < 16; ++r)
    A.enc_proj[(size_t)(m0+half*16+r)*128 + d] = acc[r] + be;
}

// ---------------- prenet ----------------
__global__ void __launch_bounds__(256) k_pre0(Args A){
  __shared__ float As[32][80];
  int m0 = blockIdx.x*32, tid = threadIdx.x;
  for (int e = tid; e < 2560; e += 256){
    int r = e/80, o = e - r*80;
    int row = m0+r; int l = row & 255, b = row >> 8;
    As[r][o] = (l==0) ? 0.f : A.ys[((size_t)b*256 + (l-1))*80 + o];
  }
  __syncthreads();
  float acc[32];
  #pragma unroll
  for (int r = 0; r < 32; ++r) acc[r] = 0.f;
  for (int o = 0; o < 80; ++o){
    float w = A.Wp0[o*256 + tid];
    #pragma unroll
    for (int r = 0; r < 32; ++r) acc[r] += As[r][o]*w;
  }
  float bb = A.bp0[tid];
  for (int r = 0; r < 32; ++r){
    float v = acc[r]+bb;
    A.pre_tmp[(size_t)(m0+r)*256 + tid] = v>0.f?v:0.f;
  }
}

__global__ void __launch_bounds__(256) k_pre1(Args A){
  __shared__ float As[32][256];
  int m0 = blockIdx.x*32, tid = threadIdx.x;
  for (int e = tid; e < 8192; e += 256){
    int r = e >> 8, j = e & 255;
    As[r][j] = A.pre_tmp[(size_t)(m0+r)*256 + j];
  }
  __syncthreads();
  float acc[32];
  #pragma unroll
  for (int r = 0; r < 32; ++r) acc[r] = 0.f;
  for (int j = 0; j < 256; ++j){
    float w = A.Wp1[j*256 + tid];
    #pragma unroll
    for (int r = 0; r < 32; ++r) acc[r] += As[r][j]*w;
  }
  float bb = A.bp1[tid];
  for (int r = 0; r < 32; ++r){
    float v = acc[r]+bb;
    A.pre_all[(size_t)(m0+r)*256 + tid] = v>0.f?v:0.f;
  }
}

// ---- stage 32 rows x 256 floats into LDS (pitch 260), coherent source ----
__device__ __forceinline__ void stage256_coh(const float* base, int rowstride, int koff,
                                             float* Xl, int tid){
  v4f r0,r1,r2,r3,r4,r5,r6,r7;
  #define LDX(i,dst) { int f=tid+((i)<<8); int b=f>>6; int jq=f&63; \
      dst = ldc4_nw(base + (size_t)b*rowstride + koff + jq*4); }
  LDX(0,r0) LDX(1,r1) LDX(2,r2) LDX(3,r3) LDX(4,r4) LDX(5,r5) LDX(6,r6) LDX(7,r7)
  #undef LDX
  waitvm4(r0,r1,r2,r3); waitvm4(r4,r5,r6,r7);
  __syncthreads();   // previous consumers of Xl are done
  #define STX(i,src) { int f=tid+((i)<<8); int b=f>>6; int jq=f&63; \
      *(v4f*)&Xl[b*260 + jq*4] = src; }
  STX(0,r0) STX(1,r1) STX(2,r2) STX(3,r3) STX(4,r4) STX(5,r5) STX(6,r6) STX(7,r7)
  #undef STX
  __syncthreads();
}
__device__ __forceinline__ void stage256_plain(const float* base, int rowstride, int koff,
                                               float* Xl, int tid){
  v4f r0,r1,r2,r3,r4,r5,r6,r7;
  #define LDX(i,dst) { int f=tid+((i)<<8); int b=f>>6; int jq=f&63; \
      dst = *(const v4f*)(base + (size_t)b*rowstride + koff + jq*4); }
  LDX(0,r0) LDX(1,r1) LDX(2,r2) LDX(3,r3) LDX(4,r4) LDX(5,r5) LDX(6,r6) LDX(7,r7)
  #undef LDX
  __syncthreads();
  #define STX(i,src) { int f=tid+((i)<<8); int b=f>>6; int jq=f&63; \
      *(v4f*)&Xl[b*260 + jq*4] = src; }
  STX(0,r0) STX(1,r1) STX(2,r2) STX(3,r3) STX(4,r4) STX(5,r5) STX(6,r6) STX(7,r7)
  #undef STX
  __syncthreads();
}

// ---- K=256 gemm chunk: W in LDS [j][32], X in LDS pitch 260; thread = 4 cols x 1 b ----
__device__ __forceinline__ void gemm256(const float* __restrict__ Wl,
                                        const float* __restrict__ Xl,
                                        int tid, v4f& acc){
  const int cg = tid & 7, b = tid >> 3;
  const float* xr = Xl + b*260;
  #pragma unroll 4
  for (int jq = 0; jq < 64; ++jq){
    v4f xv = *(const v4f*)&xr[jq*4];
    v4f w0 = *(const v4f*)&Wl[(jq*4+0)*32 + cg*4];
    v4f w1 = *(const v4f*)&Wl[(jq*4+1)*32 + cg*4];
    v4f w2 = *(const v4f*)&Wl[(jq*4+2)*32 + cg*4];
    v4f w3 = *(const v4f*)&Wl[(jq*4+3)*32 + cg*4];
    acc += xv.x*w0; acc += xv.y*w1; acc += xv.z*w2; acc += xv.w*w3;
  }
}

// store thread's 4 cols packed as P[b*2048 + u*4 + gate]
__device__ __forceinline__ void store_packed(float* P, int b, int col, const v4f& a){
  int g = col >> 9, u = col & 511;
  float* p0 = P + b*2048 + u*4 + g;
  stc(p0+0, a.x); stc(p0+4, a.y); stc(p0+8, a.z); stc(p0+12, a.w);
}

// ---------------- the scan (persistent, 5 barriers/step) ----------------
// roles: blk 0-63 "C" (Wih0-att cols, Wf slice, c0/z0 state, dec)
//        blk 64-127 "ih1" (Wih1 cols) + attention/att_c
//        blk 128-191 "hh1" (Whh1 cols) + attention/att_c
//        blk 192-255 "hh0" (Whh0 + Wih0-pre cols; first 32: c1/z1 state)
__global__ void __launch_bounds__(256, 1) k_scan(Args A){
  extern __shared__ float L[];
  const int blk = blockIdx.x, tid = threadIdx.x;
  float* ST = L;              // 8320 floats staging/scratch
  float* WA = L + 8320;       // 16384 floats: main weight slice [j<512][32]
  int rnd = 0;
  const int role = blk >> 6;
  const int slice = blk & 63;
  #define GBAR() gbar(A.bar, ++rnd, blk, tid)

  // -------- one-time LDS fills --------
  if (role == 0){
    for (int idx = tid; idx < 512*32; idx += 256){
      int j = idx >> 5, cc = idx & 31;
      WA[idx] = A.Wih0[(size_t)j*2048 + slice*32 + cc];
    }
    if (blk < 41){
      float* WF = L + 24704;  // 2048 floats: [k<1024][2 cols]
      int c0 = blk*2;
      for (int k = tid; k < 1024; k += 256){
        WF[k*2+0] = (c0   < 80) ? A.Wf[(size_t)k*80 + c0]   : A.Wq[k];
        WF[k*2+1] = (c0+1 < 80) ? A.Wf[(size_t)k*80 + c0+1] : A.Wq[k];
      }
    }
    if (blk < 32){
      float* SB = L + 26752;  // c0[512], z0loc[512]
      for (int i = tid; i < 1024; i += 256) SB[i] = 0.f;
    }
  } else if (role == 3){
    for (int idx = tid; idx < 512*32; idx += 256){
      int j = idx >> 5, cc = idx & 31;
      WA[idx] = A.Whh0[(size_t)j*2048 + slice*32 + cc];
    }
    float* WP = L + 24704;    // 8192 floats: Wih0 pre-part [j<256][32]
    for (int idx = tid; idx < 256*32; idx += 256){
      int j = idx >> 5, cc = idx & 31;
      WP[idx] = A.Wih0[(size_t)(512+j)*2048 + slice*32 + cc];
    }
    if (slice < 32){
      float* SB = L + 32896;  // c1[512], z1loc[512]
      for (int i = tid; i < 1024; i += 256) SB[i] = 0.f;
    }
  } else {
    const float* Wsrc = (role == 1) ? A.Wih1 : A.Whh1;
    for (int idx = tid; idx < 512*32; idx += 256){
      int j = idx >> 5, cc = idx & 31;
      WA[idx] = Wsrc[(size_t)j*2048 + slice*32 + cc];
    }
    float* GS = L + 24704;    // 3968 floats
    for (int e = tid; e < 3968; e += 256) GS[e] = A.G[e];
    float* EP = L + 28672;    // 64 rows x pitch 132 = 8448
    int a = blk - 64, b = a >> 2, t0 = (a & 3)*64;
    for (int idx = tid; idx < 8192; idx += 256){
      int r = idx >> 7, d = idx & 127;
      EP[r*132 + d] = A.enc_proj[((size_t)b*256 + t0 + r)*128 + d];
    }
  }
  __syncthreads();

  for (int t = 0; t < LSEQ; ++t){
    const int par = t & 1;

    // ========== Phase A: attention e->p (+z1(t-1) finalize) ==========
    if (role == 1 || role == 2){
      float* GS = L + 24704; float* EP = L + 28672;
      int a = blk - 64, b = a >> 2, t0 = (a & 3)*64;
      float* awin = ST;          // 96
      float* decs = ST + 128;    // 128
      float* gws  = ST + 384;    // 128
      float* ps   = ST + 512;    // 64
      const float* awp = (t == 0) ? (A.aw0 + b*256)
                                  : (A.out_aws + ((size_t)b*256 + (t-1))*256);
      if (tid < 94){ int ix = t0 - 15 + tid; awin[tid] = ((unsigned)ix < 256u) ? ldc(awp + ix) : 0.f; }
      if (tid < 128) gws[tid] = A.g_w[tid];
      if (tid >= 128){ int j = tid - 128; decs[j] = ldc(A.dec + b*128 + j); }
      __syncthreads();
      int tl = tid >> 2, l4 = tid & 3;
      v4f att4[8];
      #pragma unroll
      for (int i = 0; i < 8; ++i) att4[i] = (v4f){0.f,0.f,0.f,0.f};
      for (int k = 0; k < 31; ++k){
        float aw = awin[tl + k];
        const float* gp = &GS[k*128];
        #pragma unroll
        for (int i = 0; i < 8; ++i)
          att4[i] += (*(const v4f*)&gp[l4*4 + i*16]) * aw;
      }
      const float* ep = &EP[tl*132];
      float part = 0.f;
      #pragma unroll
      for (int i = 0; i < 8; ++i){
        int dd = l4*4 + i*16;
        v4f vv = att4[i] + *(const v4f*)&ep[dd] + *(const v4f*)&decs[dd];
        v4f gw4 = *(const v4f*)&gws[dd];
        part += tanhf(vv.x)*gw4.x + tanhf(vv.y)*gw4.y + tanhf(vv.z)*gw4.z + tanhf(vv.w)*gw4.w;
      }
      part += __shfl_xor(part, 1); part += __shfl_xor(part, 2);
      if (l4 == 0){
        float e = part + A.g_b[0];
        float p = (t0 + tl < A.ilens[b]) ? expf(2.0f*e) : 0.0f;
        stc(A.p_buf + b*256 + t0 + tl, p);
        ps[tl] = p;
      }
      __syncthreads();
      if (tid < 64){
        float v = ps[tid];
        v += __shfl_xor(v,1); v += __shfl_xor(v,2); v += __shfl_xor(v,4);
        v += __shfl_xor(v,8); v += __shfl_xor(v,16); v += __shfl_xor(v,32);
        if (tid == 0) stc(A.psums + b*4 + (a & 3), v);
      }
    } else if (role == 3 && slice < 32 && t > 0){
      // z1(t-1) finalize
      int b = slice;
      float* SB = L + 32896;
      int u = tid*2;
      v4f a1 = ldc4_nw(A.G1a + b*2048 + u*4);
      v4f a2 = ldc4_nw(A.G1a + b*2048 + u*4 + 4);
      v4f b1 = ldc4_nw(A.G1b + b*2048 + u*4);
      v4f b2 = ldc4_nw(A.G1b + b*2048 + u*4 + 4);
      waitvm4(a1,a2,b1,b2);
      v4f s1 = *(const v4f*)&A.biasP1[u*4];
      v4f s2 = *(const v4f*)&A.biasP1[u*4 + 4];
      {
        float gi=a1.x+b1.x+s1.x, gf=a1.y+b1.y+s1.y, gg=a1.z+b1.z+s1.z, go=a1.w+b1.w+s1.w;
        float co=SB[u], zo=SB[512+u];
        float c2=sigf(gf)*co+sigf(gi)*tanhf(gg);
        float h=sigf(go)*tanhf(c2);
        SB[u]=0.1f*co+0.9f*c2;
        float zn=0.1f*zo+0.9f*h; SB[512+u]=zn;
        stc(A.z1buf + b*512 + u, zn);
      }
      {
        int u2=u+1;
        float gi=a2.x+b2.x+s2.x, gf=a2.y+b2.y+s2.y, gg=a2.z+b2.z+s2.z, go=a2.w+b2.w+s2.w;
        float co=SB[u2], zo=SB[512+u2];
        float c2=sigf(gf)*co+sigf(gi)*tanhf(gg);
        float h=sigf(go)*tanhf(c2);
        SB[u2]=0.1f*co+0.9f*c2;
        float zn=0.1f*zo+0.9f*h; SB[512+u2]=zn;
        stc(A.z1buf + b*512 + u2, zn);
      }
    }
    GBAR();

    // ========== Phase B: att_c  (+ out(t-1) on C-blocks) ==========
    if (role == 1 || role == 2){
      int a = blk - 64, b = a >> 2, dsl = (a & 3)*128;
      float* Sp = ST; float* red = ST + 256;
      Sp[tid] = ldc(A.p_buf + b*256 + tid);
      v4f pv = ldc4(A.psums + b*4);
      float inv = 1.0f/(pv.x + pv.y + pv.z + pv.w);
      __syncthreads();
      int d = tid & 127, qh = tid >> 7;
      const float* ez = A.enc_z + ((size_t)(b*256 + qh*128))*512 + dsl + d;
      float part = 0.f;
      #pragma unroll 4
      for (int q = 0; q < 128; ++q) part += Sp[qh*128 + q]*ez[(size_t)q*512];
      red[tid] = part;
      __syncthreads();
      if (tid < 128)
        stc(A.att_c + par*16384 + b*512 + dsl + tid, (red[tid] + red[128+tid])*inv);
      if ((a & 3) == 0)
        stc(A.out_aws + ((size_t)b*256 + t)*256 + tid, Sp[tid]*inv);
    } else if (role == 0 && blk < 41 && t > 0){
      // out(t-1): cols 2*blk, 2*blk+1 of [Wf | Wq]
      int tt = t - 1;
      float* Xl = ST; float* WF = L + 24704;
      int b = tid >> 3, sub = tid & 7;
      float acc0 = 0.f, acc1 = 0.f;
      for (int pass = 0; pass < 4; ++pass){
        const float* src = (pass < 2) ? A.z1buf : (A.att_c + (tt & 1)*16384);
        int koff = (pass & 1)*256;
        v4f r0,r1,r2,r3,r4,r5,r6,r7;
        #define LDO(i,dst) { int f=tid+((i)<<8); int b2=f>>6; int jq=f&63; \
            dst = ldc4_nw(src + (size_t)b2*512 + koff + jq*4); }
        LDO(0,r0) LDO(1,r1) LDO(2,r2) LDO(3,r3) LDO(4,r4) LDO(5,r5) LDO(6,r6) LDO(7,r7)
        #undef LDO
        waitvm4(r0,r1,r2,r3); waitvm4(r4,r5,r6,r7);
        __syncthreads();
        #define STO(i,src2) { int f=tid+((i)<<8); int b2=f>>6; int jq=f&63; \
            *(v4f*)&Xl[b2*260 + jq*4] = src2; }
        STO(0,r0) STO(1,r1) STO(2,r2) STO(3,r3) STO(4,r4) STO(5,r5) STO(6,r6) STO(7,r7)
        #undef STO
        __syncthreads();
        int kbase = pass*256;
        #pragma unroll 4
        for (int i = 0; i < 32; ++i){
          int k = sub + 8*i;
          float x = Xl[b*260 + k];
          acc0 += x*WF[(kbase+k)*2 + 0];
          acc1 += x*WF[(kbase+k)*2 + 1];
        }
        __syncthreads();
      }
      float* red = ST;
      red[(b*8+sub)*2+0] = acc0; red[(b*8+sub)*2+1] = acc1;
      __syncthreads();
      if (tid < 64){
        int b2 = tid >> 1, e = tid & 1, cg = blk*2 + e;
        float v = (cg < 80) ? A.bf[cg] : A.bq[0];
        for (int s = 0; s < 8; ++s) v += red[(b2*8+s)*2 + e];
        if (cg < 80){
          A.out_before[((size_t)b2*256 + tt)*80 + cg] = v;
          A.before_t[((size_t)b2*80 + cg)*256 + tt] = v;
        } else if (cg == 80){
          A.out_logits[(size_t)b2*256 + tt] = v;
        }
      }
    }
    GBAR();

    // ========== Phase C: G0a = att_c@Wih0a ; gpre1 = pre(t)@Wih0p ==========
    if (role == 0){
      v4f acc = {0.f,0.f,0.f,0.f};
      const float* src = A.att_c + par*16384;
      stage256_coh(src, 512, 0, ST, tid);
      gemm256(WA, ST, tid, acc);
      stage256_coh(src, 512, 256, ST, tid);
      gemm256(WA + 8192, ST, tid, acc);
      store_packed(A.G0a, tid >> 3, slice*32 + (tid & 7)*4, acc);
    } else if (role == 3){
      float* WP = L + 24704;
      v4f acc = {0.f,0.f,0.f,0.f};
      stage256_plain(A.pre_all + (size_t)t*256, 65536, 0, ST, tid);
      gemm256(WP, ST, tid, acc);
      store_packed(A.gpre1, tid >> 3, slice*32 + (tid & 7)*4, acc);
    }
    GBAR();

    // ========== Phase C2: z0 finalize ==========
    if (role == 0 && blk < 32){
      int b = blk;
      float* SB = L + 26752;
      int u = tid*2;
      v4f g1 = ldc4_nw(A.G0a   + b*2048 + u*4);
      v4f g2 = ldc4_nw(A.G0a   + b*2048 + u*4 + 4);
      v4f p1 = ldc4_nw(A.gpre0 + b*2048 + u*4);
      v4f p2 = ldc4_nw(A.gpre0 + b*2048 + u*4 + 4);
      v4f q1 = ldc4_nw(A.gpre1 + b*2048 + u*4);
      v4f q2 = ldc4_nw(A.gpre1 + b*2048 + u*4 + 4);
      waitvm4(g1,g2,p1,p2); waitvm2(q1,q2);
      v4f s1 = *(const v4f*)&A.biasP0[u*4];
      v4f s2 = *(const v4f*)&A.biasP0[u*4 + 4];
      {
        float gi=g1.x+p1.x+q1.x+s1.x, gf=g1.y+p1.y+q1.y+s1.y;
        float gg=g1.z+p1.z+q1.z+s1.z, go=g1.w+p1.w+q1.w+s1.w;
        float co=SB[u], zo=SB[512+u];
        float c2=sigf(gf)*co+sigf(gi)*tanhf(gg);
        float h=sigf(go)*tanhf(c2);
        SB[u]=0.1f*co+0.9f*c2;
        float zn=0.1f*zo+0.9f*h; SB[512+u]=zn;
        stc(A.z0 + b*512 + u, zn);
      }
      {
        int u2=u+1;
        float gi=g2.x+p2.x+q2.x+s2.x, gf=g2.y+p2.y+q2.y+s2.y;
        float gg=g2.z+p2.z+q2.z+s2.z, go=g2.w+p2.w+q2.w+s2.w;
        float co=SB[u2], zo=SB[512+u2];
        float c2=sigf(gf)*co+sigf(gi)*tanhf(gg);
        float h=sigf(go)*tanhf(c2);
        SB[u2]=0.1f*co+0.9f*c2;
        float zn=0.1f*zo+0.9f*h; SB[512+u2]=zn;
        stc(A.z0 + b*512 + u2, zn);
      }
    }
    GBAR();

    // ========== Phase D: G1a, G1b, gpre0(t+1), dec(t+1) ==========
    if (role == 1){
      v4f acc = {0.f,0.f,0.f,0.f};
      stage256_coh(A.z0, 512, 0, ST, tid);
      gemm256(WA, ST, tid, acc);
      stage256_coh(A.z0, 512, 256, ST, tid);
      gemm256(WA + 8192, ST, tid, acc);
      store_packed(A.G1a, tid >> 3, slice*32 + (tid & 7)*4, acc);
    } else if (role == 2){
      v4f acc = {0.f,0.f,0.f,0.f};
      stage256_coh(A.z1buf, 512, 0, ST, tid);
      gemm256(WA, ST, tid, acc);
      stage256_coh(A.z1buf, 512, 256, ST, tid);
      gemm256(WA + 8192, ST, tid, acc);
      store_packed(A.G1b, tid >> 3, slice*32 + (tid & 7)*4, acc);
    } else if (role == 3){
      v4f acc = {0.f,0.f,0.f,0.f};
      stage256_coh(A.z0, 512, 0, ST, tid);
      gemm256(WA, ST, tid, acc);
      stage256_coh(A.z0, 512, 256, ST, tid);
      gemm256(WA + 8192, ST, tid, acc);
      store_packed(A.gpre0, tid >> 3, slice*32 + (tid & 7)*4, acc);
    } else if (blk < 32){
      int b = blk;
      float* zs = ST;
      if (tid < 128){ v4f v = ldc4(A.z0 + b*512 + tid*4); *(v4f*)&zs[tid*4] = v; }
      __syncthreads();
      int d = tid & 127, kh = tid >> 7;
      float part = 0.f;
      #pragma unroll 4
      for (int j = 0; j < 256; ++j)
        part += zs[kh*256 + j]*A.W_dec[(size_t)(kh*256 + j)*128 + d];
      float* red = ST + 1024;
      red[tid] = part;
      __syncthreads();
      if (tid < 128) stc(A.dec + b*128 + tid, red[tid] + red[128+tid]);
    }
    GBAR();
  }

  // ========== tail: finalize z1(255), then out(255) ==========
  if (role == 3 && slice < 32){
    int b = slice;
    float* SB = L + 32896;
    int u = tid*2;
    v4f a1 = ldc4_nw(A.G1a + b*2048 + u*4);
    v4f a2 = ldc4_nw(A.G1a + b*2048 + u*4 + 4);
    v4f b1 = ldc4_nw(A.G1b + b*2048 + u*4);
    v4f b2 = ldc4_nw(A.G1b + b*2048 + u*4 + 4);
    waitvm4(a1,a2,b1,b2);
    v4f s1 = *(const v4f*)&A.biasP1[u*4];
    v4f s2 = *(const v4f*)&A.biasP1[u*4 + 4];
    {
      float gi=a1.x+b1.x+s1.x, gf=a1.y+b1.y+s1.y, gg=a1.z+b1.z+s1.z, go=a1.w+b1.w+s1.w;
      float co=SB[u], zo=SB[512+u];
      float c2=sigf(gf)*co+sigf(gi)*tanhf(gg);
      float h=sigf(go)*tanhf(c2);
      float zn=0.1f*zo+0.9f*h;
      stc(A.z1buf + b*512 + u, zn);
    }
    {
      int u2=u+1;
      float gi=a2.x+b2.x+s2.x, gf=a2.y+b2.y+s2.y, gg=a2.z+b2.z+s2.z, go=a2.w+b2.w+s2.w;
      float co=SB[u2], zo=SB[512+u2];
      float c2=sigf(gf)*co+sigf(gi)*tanhf(gg);
      float h=sigf(go)*tanhf(c2);
      float zn=0.1f*zo+0.9f*h;
      stc(A.z1buf + b*512 + u2, zn);
    }
  }
  GBAR();
  if (role == 0 && blk < 41){
    int tt = 255;
    float* Xl = ST; float* WF = L + 24704;
    int b = tid >> 3, sub = tid & 7;
    float acc0 = 0.f, acc1 = 0.f;
    for (int pass = 0; pass < 4; ++pass){
      const float* src = (pass < 2) ? A.z1buf : (A.att_c + (tt & 1)*16384);
      int koff = (pass & 1)*256;
      v4f r0,r1,r2,r3,r4,r5,r6,r7;
      #define LDO(i,dst) { int f=tid+((i)<<8); int b2=f>>6; int jq=f&63; \
          dst = ldc4_nw(src + (size_t)b2*512 + koff + jq*4); }
      LDO(0,r0) LDO(1,r1) LDO(2,r2) LDO(3,r3) LDO(4,r4) LDO(5,r5) LDO(6,r6) LDO(7,r7)
      #undef LDO
      waitvm4(r0,r1,r2,r3); waitvm4(r4,r5,r6,r7);
      __syncthreads();
      #define STO(i,src2) { int f=tid+((i)<<8); int b2=f>>6; int jq=f&63; \
          *(v4f*)&Xl[b2*260 + jq*4] = src2; }
      STO(0,r0) STO(1,r1) STO(2,r2) STO(3,r3) STO(4,r4) STO(5,r5) STO(6,r6) STO(7,r7)
      #undef STO
      __syncthreads();
      int kbase = pass*256;
      #pragma unroll 4
      for (int i = 0; i < 32; ++i){
        int k = sub + 8*i;
        float x = Xl[b*260 + k];
        acc0 += x*WF[(kbase+k)*2 + 0];
        acc1 += x*WF[(kbase+k)*2 + 1];
      }
      __syncthreads();
    }
    float* red = ST;
    red[(b*8+sub)*2+0] = acc0; red[(b*8+sub)*2+1] = acc1;
    __syncthreads();
    if (tid < 64){
      int b2 = tid >> 1, e = tid & 1, cg = blk*2 + e;
      float v = (cg < 80) ? A.bf[cg] : A.bq[0];
      for (int s = 0; s < 8; ++s) v += red[(b2*8+s)*2 + e];
      if (cg < 80){
        A.out_before[((size_t)b2*256 + tt)*80 + cg] = v;
        A.before_t[((size_t)b2*80 + cg)*256 + tt] = v;
      } else if (cg == 80){
        A.out_logits[(size_t)b2*256 + tt] = v;
      }
    }
  }
  #undef GBAR
}

// ---------------- postnet conv (kernel=5, pad=2) as tiled GEMM ----------------
__global__ void __launch_bounds__(256) k_conv(const float* __restrict__ in,
                       const float* __restrict__ Wt,
                       const float* __restrict__ sc, const float* __restrict__ sh,
                       float* __restrict__ out0, const float* __restrict__ before,
                       float* __restrict__ after, int C, int N, int mode)
{
  __shared__ __align__(16) float As[16][64];
  __shared__ __align__(16) float Bs[16][64];
  int bx = blockIdx.x;
  int b = bx >> 2, l0 = (bx & 3)*64;
  int n0 = blockIdx.y*64;
  int tid = threadIdx.x, tx = tid & 15, ty = tid >> 4;
  float acc[4][4];
  #pragma unroll
  for (int i = 0; i < 4; ++i)
    #pragma unroll
    for (int j = 0; j < 4; ++j) acc[i][j] = 0.f;
  for (int k = 0; k < 5; ++k){
    int shift = k - 2;
    for (int c0 = 0; c0 < C; c0 += 16){
      #pragma unroll
      for (int i = 0; i < 4; ++i){
        int e = tid + i*256; int cc = e >> 6, ll = e & 63;
        int l = l0 + ll + shift;
        As[cc][ll] = ((unsigned)l < 256u) ? in[((size_t)(b*C + c0+cc))*256 + l] : 0.f;
        int n = n0 + ll;
        Bs[cc][ll] = (n < N) ? Wt[((size_t)k*C + c0+cc)*(size_t)N + n] : 0.f;
      }
      __syncthreads();
      #pragma unroll
      for (int cc = 0; cc < 16; ++cc){
        const float4 av = *reinterpret_cast<const float4*>(&As[cc][ty<<2]);
        const float4 bv = *reinterpret_cast<const float4*>(&Bs[cc][tx<<2]);
        acc[0][0]+=av.x*bv.x; acc[0][1]+=av.x*bv.y; acc[0][2]+=av.x*bv.z; acc[0][3]+=av.x*bv.w;
        acc[1][0]+=av.y*bv.x; acc[1][1]+=av.y*bv.y; acc[1][2]+=av.y*bv.z; acc[1][3]+=av.y*bv.w;
        acc[2][0]+=av.z*bv.x; acc[2][1]+=av.z*bv.y; acc[2][2]+=av.z*bv.z; acc[2][3]+=av.z*bv.w;
        acc[3][0]+=av.w*bv.x; acc[3][1]+=av.w*bv.y; acc[3][2]+=av.w*bv.z; acc[3][3]+=av.w*bv.w;
      }
      __syncthreads();
    }
  }
  #pragma unroll
  for (int i = 0; i < 4; ++i){
    int l = l0 + (ty<<2) + i;
    #pragma unroll
    for (int j = 0; j < 4; ++j){
      int n = n0 + (tx<<2) + j;
      if (n < N){
        float v = sc[n]*acc[i][j] + sh[n];
        if (mode == 0){
          out0[((size_t)(b*N + n))*256 + l] = tanhf(v);
        } else {
          size_t ob = ((size_t)b*256 + l)*80 + n;
          after[ob] = before[ob] + v;
        }
      }
    }
  }
}

extern "C" void kernel_launch(void* const* d_in, const int* in_sizes, int n_in,
                              void* d_out, int out_size, void* d_ws, size_t ws_size,
                              hipStream_t stream) {
  Args A;
  A.enc_z = (const float*)d_in[0];  A.ys = (const float*)d_in[1];
  A.ilens = (const int*)d_in[3];
  A.W_enc = (const float*)d_in[4];  A.b_enc = (const float*)d_in[5];
  A.W_dec = (const float*)d_in[6];  A.loc_kernel = (const float*)d_in[7];
  A.W_att = (const float*)d_in[8];  A.g_w = (const float*)d_in[9];  A.g_b = (const float*)d_in[10];
  A.Wp0 = (const float*)d_in[11];   A.bp0 = (const float*)d_in[12];
  A.Wp1 = (const float*)d_in[13];   A.bp1 = (const float*)d_in[14];
  A.Wih0 = (const float*)d_in[15];  A.Whh0 = (const float*)d_in[16];
  A.bih0 = (const float*)d_in[17];  A.bhh0 = (const float*)d_in[18];
  A.Wih1 = (const float*)d_in[19];  A.Whh1 = (const float*)d_in[20];
  A.bih1 = (const float*)d_in[21];  A.bhh1 = (const float*)d_in[22];
  A.Wf = (const float*)d_in[23];    A.bf = (const float*)d_in[24];
  A.Wq = (const float*)d_in[25];    A.bq = (const float*)d_in[26];
  A.pk0 = (const float*)d_in[27];   A.pb0 = (const float*)d_in[28];
  A.bg0 = (const float*)d_in[29];   A.bb0 = (const float*)d_in[30];
  A.pk1 = (const float*)d_in[31];   A.pb1 = (const float*)d_in[32];
  A.bg1 = (const float*)d_in[33];   A.bb1 = (const float*)d_in[34];
  A.pk2 = (const float*)d_in[35];   A.pb2 = (const float*)d_in[36];
  A.bg2 = (const float*)d_in[37];   A.bb2 = (const float*)d_in[38];

  float* ws = (float*)d_ws;
  size_t off = 0;
  auto alloc = [&](size_t n){ float* p = ws + off; off += n; return p; };
  A.enc_proj   = alloc(1048576);
  A.pre_tmp    = alloc(2097152);
  A.pre_all    = alloc(2097152);
  A.G          = alloc(3968);
  A.aw0        = alloc(8192);
  A.p_buf      = alloc(8192);
  A.psums      = alloc(128);
  A.dec        = alloc(4096);
  A.att_c      = alloc(32768);
  A.z0         = alloc(16384);
  A.z1buf      = alloc(16384);
  A.G0a        = alloc(65536);
  A.G1a        = alloc(65536);
  A.G1b        = alloc(65536);
  A.gpre0      = alloc(65536);
  A.gpre1      = alloc(65536);
  A.biasP0     = alloc(2048);
  A.biasP1     = alloc(2048);
  A.before_t   = alloc(655360);
  A.h0         = alloc(4194304);
  A.h1         = alloc(4194304);
  A.Wt0        = alloc(204800);
  A.Wt1        = alloc(1310720);
  A.Wt2        = alloc(204800);
  A.s0 = alloc(512); A.t0s = alloc(512);
  A.s1 = alloc(512); A.t1s = alloc(512);
  A.s2 = alloc(128); A.t2s = alloc(128);
  A.bar = (int*)(ws + off); off += 512;

  float* out = (float*)d_out;
  A.out_after  = out;
  A.out_before = out + 655360;
  A.out_logits = out + 1310720;
  A.out_aws    = out + 1318912;

  hipFuncSetAttribute((const void*)k_scan,
                      hipFuncAttributeMaxDynamicSharedMemorySize, DYN_LDS_BYTES);

  k_init<<<dim3(512), dim3(256), 0, stream>>>(A);
  k_encproj<<<dim3(256), dim3(256), 0, stream>>>(A);
  k_pre0<<<dim3(256), dim3(256), 0, stream>>>(A);
  k_pre1<<<dim3(256), dim3(256), 0, stream>>>(A);
  k_scan<<<dim3(NBLK), dim3(256), DYN_LDS_BYTES, stream>>>(A);
  k_conv<<<dim3(128,8), dim3(256), 0, stream>>>(A.before_t, A.Wt0, A.s0, A.t0s, A.h0, nullptr, nullptr, 80, 512, 0);
  k_conv<<<dim3(128,8), dim3(256), 0, stream>>>(A.h0, A.Wt1, A.s1, A.t1s, A.h1, nullptr, nullptr, 512, 512, 0);
  k_conv<<<dim3(128,2), dim3(256), 0, stream>>>(A.h1, A.Wt2, A.s2, A.t2s, nullptr, A.out_before, A.out_after, 512, 80, 1);
}